// Round 4
// baseline (3223.337 us; speedup 1.0000x reference)
//
#include <hip/hip_runtime.h>

#define N_USERS 60000
#define N_ITEMS 40000
#define N_TOTAL 100000
#define EMB 64
#define LN_EPS 1e-5f

#define KPB 64                                  // keys per coarse bucket
#define NBUCK ((N_TOTAL + KPB - 1) / KPB)       // 1563
#define NSHARD 8                                // XCD shards
#define CNT (NBUCK * NSHARD)                    // 12504 (bucket,shard) bins
#define SNCH ((CNT + 255) / 256)                // 49 scan chunks

// ---------------------------------------------------------------------------
// ego2[r,:] = c * filt[r] * (x[r,:] @ W) + x[r,:]
__global__ void transform_kernel(const float* __restrict__ x,
                                 const float* __restrict__ W,
                                 const float* __restrict__ filt,
                                 const float* __restrict__ par,
                                 float* __restrict__ out, int nrows)
{
    __shared__ float Ws[EMB * EMB];
    const int tid = threadIdx.x;
    for (int i = tid; i < EMB * EMB; i += blockDim.x) Ws[i] = W[i];
    __syncthreads();
    const float c = par[0] * par[1];
    const int lane = tid & 63;
    const int wave = tid >> 6;            // 4 waves/block
    const int r0 = blockIdx.x * 32;       // 32 rows per block
    for (int rr = wave; rr < 32; rr += 4) {
        const int r = r0 + rr;
        if (r >= nrows) break;
        const float xv = x[(size_t)r * EMB + lane];
        float acc = 0.f;
#pragma unroll
        for (int k = 0; k < EMB; ++k) {
            const float xk = __shfl(xv, k, 64);
            acc += xk * Ws[k * EMB + lane];
        }
        out[(size_t)r * EMB + lane] = c * filt[r] * acc + xv;
    }
}

// ---------------------------------------------------------------------------
// Histogram over (bucket, shard) for BOTH orderings in one pass.
// shard = blockIdx.x & 7 — must match build_buckets' grid/block mapping.
__global__ void hist2_kernel(const int* __restrict__ rows,
                             const int* __restrict__ cols,
                             int* __restrict__ cnt_row,
                             int* __restrict__ cnt_col, int nnz)
{
    const int e = blockIdx.x * blockDim.x + threadIdx.x;
    if (e >= nnz) return;
    const int sh = blockIdx.x & (NSHARD - 1);
    atomicAdd(&cnt_row[(rows[e] >> 6) * NSHARD + sh], 1);
    atomicAdd(&cnt_col[(cols[e] >> 6) * NSHARD + sh], 1);
}

// Phase A: per-256-chunk sums of a0/a1.  grid = (SNCH, 2).
__global__ void chunk_sums(const int* __restrict__ a0,
                           const int* __restrict__ a1,
                           int* __restrict__ bsum, int n)
{
    const int* a = blockIdx.y ? a1 : a0;
    const int i = blockIdx.x * 256 + threadIdx.x;
    int v = (i < n) ? a[i] : 0;
    __shared__ int ws[4];
    const int lane = threadIdx.x & 63;
    const int wv = threadIdx.x >> 6;
#pragma unroll
    for (int off = 32; off > 0; off >>= 1) v += __shfl_down(v, off, 64);
    if (lane == 0) ws[wv] = v;
    __syncthreads();
    if (threadIdx.x == 0)
        bsum[blockIdx.y * SNCH + blockIdx.x] = ws[0] + ws[1] + ws[2] + ws[3];
}

// Phase B: exclusive scan of each array's chunk sums (SNCH<=256). grid = 2.
__global__ void scan_sums(int* __restrict__ bsum)
{
    int* a = bsum + blockIdx.x * SNCH;
    __shared__ int wsum[4];
    const int lane = threadIdx.x & 63;
    const int wv = threadIdx.x >> 6;
    const int i = threadIdx.x;
    const int v = (i < SNCH) ? a[i] : 0;
    int incl = v;
#pragma unroll
    for (int off = 1; off < 64; off <<= 1) {
        const int t = __shfl_up(incl, off, 64);
        if (lane >= off) incl += t;
    }
    if (lane == 63) wsum[wv] = incl;
    __syncthreads();
    int woff = 0;
    for (int w = 0; w < wv; ++w) woff += wsum[w];
    if (i < SNCH) a[i] = woff + incl - v;           // exclusive prefix
}

// Phase C: block-local exclusive scan + chunk offset. grid = (SNCH, 2).
__global__ void scan_apply(int* __restrict__ a0, int* __restrict__ a1,
                           const int* __restrict__ bsum, int n)
{
    int* a = blockIdx.y ? a1 : a0;
    const int chunk_off = bsum[blockIdx.y * SNCH + blockIdx.x];
    const int i = blockIdx.x * 256 + threadIdx.x;
    const int v = (i < n) ? a[i] : 0;
    const int lane = threadIdx.x & 63;
    const int wv = threadIdx.x >> 6;
    int incl = v;
#pragma unroll
    for (int off = 1; off < 64; off <<= 1) {
        const int t = __shfl_up(incl, off, 64);
        if (lane >= off) incl += t;
    }
    __shared__ int wsum[4];
    if (lane == 63) wsum[wv] = incl;
    __syncthreads();
    int woff = chunk_off;
    for (int w = 0; w < wv; ++w) woff += wsum[w];
    if (i < n) a[i] = woff + incl - v;              // exclusive prefix
}

// ---------------------------------------------------------------------------
// Scatter edges into (bucket, shard) regions. cursor: exclusive starts on
// entry, END offsets on exit. Payload packs other(17b) | keylow(6b)<<20.
// shard = blockIdx.x & 7 ~ XCD id (round-robin dispatch) so the 8 appends
// filling one 64B line come from ONE L2 -> full-line writeback.
__global__ void build_buckets(const int* __restrict__ key,
                              const int* __restrict__ other,
                              const float* __restrict__ vals,
                              int* __restrict__ cursor,
                              int2* __restrict__ pairs, int nnz)
{
    const int e = blockIdx.x * blockDim.x + threadIdx.x;
    if (e >= nnz) return;
    const int k = key[e];
    const int sh = blockIdx.x & (NSHARD - 1);
    const int p = atomicAdd(&cursor[(k >> 6) * NSHARD + sh], 1);
    pairs[p] = make_int2(other[e] | ((k & 63) << 20), __float_as_int(vals[e]));
}

// One block per bucket: accumulate 64 destination rows in a 16 KB LDS tile
// via ds_add_f32, streaming the bucket's edges; write the tile once.
// ends = cursor after build (bin END offsets, lexicographic (bucket,shard)).
__global__ void bucket_pull(const int* __restrict__ ends,
                            const int2* __restrict__ pairs,
                            const float* __restrict__ src,
                            float* __restrict__ dst, int nrows)
{
    __shared__ float acc[KPB * EMB];            // 16 KB
    const int b = blockIdx.x;
    const int tid = threadIdx.x;
    for (int i = tid; i < KPB * EMB; i += 256) acc[i] = 0.f;
    __syncthreads();

    const int beg = b ? ends[b * NSHARD - 1] : 0;   // end of previous bucket
    const int end = ends[b * NSHARD + (NSHARD - 1)];
    const int lane = tid & 63;
    const int wv = tid >> 6;

    int j = beg + wv;                            // 4 waves, stride 4, unroll 2
    for (; j + 4 < end; j += 8) {
        const int2 p0 = pairs[j];
        const int2 p1 = pairs[j + 4];
        const float s0 = src[(p0.x & 0xFFFFF) * EMB + lane];
        const float s1 = src[(p1.x & 0xFFFFF) * EMB + lane];
        atomicAdd(&acc[(p0.x >> 20) * EMB + lane], __int_as_float(p0.y) * s0);
        atomicAdd(&acc[(p1.x >> 20) * EMB + lane], __int_as_float(p1.y) * s1);
    }
    if (j < end) {
        const int2 p = pairs[j];
        const float s = src[(p.x & 0xFFFFF) * EMB + lane];
        atomicAdd(&acc[(p.x >> 20) * EMB + lane], __int_as_float(p.y) * s);
    }
    __syncthreads();

    for (int i = tid; i < KPB * EMB; i += 256) {
        const int r = b * KPB + (i >> 6);
        if (r < nrows) dst[(size_t)r * EMB + (i & 63)] = acc[i];
    }
}

// ---------------------------------------------------------------------------
// Fallback (round-1) atomic scatter, used only if ws_size is too small.
__global__ void spmm_scatter(const int* __restrict__ src_idx,
                             const int* __restrict__ dst_idx,
                             const float* __restrict__ vals,
                             const float* __restrict__ src,
                             float* __restrict__ dst, int nnz)
{
    const long long t = (long long)blockIdx.x * blockDim.x + threadIdx.x;
    const int e = (int)(t >> 4);
    const int l = (int)(t & 15);
    if (e >= nnz) return;
    const int s = src_idx[e];
    const int d = dst_idx[e];
    const float v = vals[e];
    const float4 xv = ((const float4*)(src + (size_t)s * EMB))[l];
    float* dp = dst + (size_t)d * EMB + l * 4;
    atomicAdd(dp + 0, v * xv.x);
    atomicAdd(dp + 1, v * xv.y);
    atomicAdd(dp + 2, v * xv.z);
    atomicAdd(dp + 3, v * xv.w);
}

// ---------------------------------------------------------------------------
// out[r,:] = LN(y[r,:]) * gamma + beta + ego[r,:]   (in-place safe: out==y)
__global__ void ln_residual(const float* y,
                            const float* __restrict__ ego,
                            const float* __restrict__ gamma,
                            const float* __restrict__ beta,
                            float* out, int nrows)
{
    const int lane = threadIdx.x & 63;
    const int wave = threadIdx.x >> 6;
    const int r = blockIdx.x * 4 + wave;
    if (r >= nrows) return;
    const float v = y[(size_t)r * EMB + lane];
    float s = v, s2 = v * v;
#pragma unroll
    for (int off = 32; off > 0; off >>= 1) {
        s  += __shfl_down(s,  off, 64);
        s2 += __shfl_down(s2, off, 64);
    }
    s  = __shfl(s,  0, 64);
    s2 = __shfl(s2, 0, 64);
    const float mu  = s * (1.0f / EMB);
    const float var = s2 * (1.0f / EMB) - mu * mu;
    const float inv = rsqrtf(var + LN_EPS);
    out[(size_t)r * EMB + lane] =
        (v - mu) * inv * gamma[lane] + beta[lane] + ego[(size_t)r * EMB + lane];
}

extern "C" void kernel_launch(void* const* d_in, const int* in_sizes, int n_in,
                              void* d_out, int out_size, void* d_ws, size_t ws_size,
                              hipStream_t stream)
{
    const float* ego     = (const float*)d_in[0];
    const int*   rows    = (const int*)  d_in[1];
    const int*   cols    = (const int*)  d_in[2];
    const float* vals    = (const float*)d_in[3];
    const float* w_uu    = (const float*)d_in[4];
    const float* filt_uu = (const float*)d_in[5];
    const float* par_uu  = (const float*)d_in[6];
    const float* w_ii    = (const float*)d_in[7];
    const float* filt_ii = (const float*)d_in[8];
    const float* par_ii  = (const float*)d_in[9];
    const float* gamma   = (const float*)d_in[10];
    const float* beta    = (const float*)d_in[11];
    float* out = (float*)d_out;
    const int nnz = in_sizes[1];

    const size_t emb_elems = (size_t)N_TOTAL * EMB;
    const size_t emb_bytes = emb_elems * sizeof(float);
    float* ego2 = (float*)d_ws;                 // [0, 25.6 MB)
    float* h    = ego2 + emb_elems;             // [25.6, 51.2 MB)

    // Fast-path workspace (same bound as round 2/3 — branch stays stable).
    const size_t need = 2 * emb_bytes + (size_t)nnz * sizeof(int2)
                        + (2 * (size_t)CNT + 2 * SNCH) * sizeof(int);

    const int eb = (nnz + 255) / 256;           // edge-parallel blocks
    const int rb = (N_TOTAL + 3) / 4;           // row-parallel blocks

    if (ws_size >= need) {
        // -------- fast path: sharded coarse buckets + fused LDS pull -----
        int2* pairs    = (int2*)(h + emb_elems);          // [51.2, 76.8 MB)
        int*  offs_col = (int*)(pairs + nnz);             // CNT ints
        int*  offs_row = offs_col + CNT;                  // CNT ints
        int*  bsum     = offs_row + CNT;                  // 2*SNCH ints

        hipMemsetAsync(offs_col, 0, 2 * (size_t)CNT * sizeof(int), stream);

        hist2_kernel<<<eb, 256, 0, stream>>>(rows, cols, offs_row, offs_col, nnz);

        // Exclusive scan of both (bucket,shard) count arrays.
        chunk_sums<<<dim3(SNCH, 2), 256, 0, stream>>>(offs_col, offs_row,
                                                      bsum, CNT);
        scan_sums<<<2, 256, 0, stream>>>(bsum);
        scan_apply<<<dim3(SNCH, 2), 256, 0, stream>>>(offs_col, offs_row,
                                                      bsum, CNT);

        // Dense transforms.
        transform_kernel<<<(N_USERS + 31) / 32, 256, 0, stream>>>(
            ego, w_uu, filt_uu, par_uu, ego2, N_USERS);
        transform_kernel<<<(N_ITEMS + 31) / 32, 256, 0, stream>>>(
            ego + (size_t)N_USERS * EMB, w_ii, filt_ii, par_ii,
            ego2 + (size_t)N_USERS * EMB, N_ITEMS);

        // Pass 1: h[c] = sum val * ego2[r]  — bucket by col, payload row.
        build_buckets<<<eb, 256, 0, stream>>>(cols, rows, vals, offs_col,
                                              pairs, nnz);
        bucket_pull<<<NBUCK, 256, 0, stream>>>(offs_col, pairs, ego2, h,
                                               N_TOTAL);

        // Pass 2: y[r] = sum val * h[c]  — bucket by row, payload col.
        build_buckets<<<eb, 256, 0, stream>>>(rows, cols, vals, offs_row,
                                              pairs, nnz);
        bucket_pull<<<NBUCK, 256, 0, stream>>>(offs_row, pairs, h, out,
                                               N_TOTAL);
    } else {
        // ---------------- fallback: atomic scatter (round-1) -------------
        hipMemsetAsync(h,   0, emb_bytes, stream);
        hipMemsetAsync(out, 0, emb_bytes, stream);

        transform_kernel<<<(N_USERS + 31) / 32, 256, 0, stream>>>(
            ego, w_uu, filt_uu, par_uu, ego2, N_USERS);
        transform_kernel<<<(N_ITEMS + 31) / 32, 256, 0, stream>>>(
            ego + (size_t)N_USERS * EMB, w_ii, filt_ii, par_ii,
            ego2 + (size_t)N_USERS * EMB, N_ITEMS);

        const long long thr = (long long)nnz * 16;
        const int sblocks = (int)((thr + 255) / 256);
        spmm_scatter<<<sblocks, 256, 0, stream>>>(rows, cols, vals, ego2, h, nnz);
        spmm_scatter<<<sblocks, 256, 0, stream>>>(cols, rows, vals, h, out, nnz);
    }

    // LayerNorm + residual, in place on d_out.
    ln_residual<<<rb, 256, 0, stream>>>(out, ego, gamma, beta, out, N_TOTAL);
}

// Round 5
// 634.903 us; speedup vs baseline: 5.0769x; 5.0769x over previous
//
#include <hip/hip_runtime.h>

#define N_USERS 60000
#define N_ITEMS 40000
#define N_TOTAL 100000
#define EMB 64
#define LN_EPS 1e-5f

#define KPS 512                                  // keys per super-bucket
#define NSUP ((N_TOTAL + KPS - 1) / KPS)         // 196
#define EPB 4096                                 // edges per build_l1 block

// ---------------------------------------------------------------------------
// ego2[r,:] = c * filt[r] * (x[r,:] @ W) + x[r,:]
__global__ void transform_kernel(const float* __restrict__ x,
                                 const float* __restrict__ W,
                                 const float* __restrict__ filt,
                                 const float* __restrict__ par,
                                 float* __restrict__ out, int nrows)
{
    __shared__ float Ws[EMB * EMB];
    const int tid = threadIdx.x;
    for (int i = tid; i < EMB * EMB; i += blockDim.x) Ws[i] = W[i];
    __syncthreads();
    const float c = par[0] * par[1];
    const int lane = tid & 63;
    const int wave = tid >> 6;
    const int r0 = blockIdx.x * 32;
    for (int rr = wave; rr < 32; rr += 4) {
        const int r = r0 + rr;
        if (r >= nrows) break;
        const float xv = x[(size_t)r * EMB + lane];
        float acc = 0.f;
#pragma unroll
        for (int k = 0; k < EMB; ++k) {
            const float xk = __shfl(xv, k, 64);
            acc += xk * Ws[k * EMB + lane];
        }
        out[(size_t)r * EMB + lane] = c * filt[r] * acc + xv;
    }
}

// ---------------------------------------------------------------------------
// Super-bucket histograms for BOTH orderings. LDS-local then merge (512 blocks
// -> only ~200k global atomics over 392 counters).
__global__ void hist_sup(const int* __restrict__ rows,
                         const int* __restrict__ cols,
                         int* __restrict__ cnt_r,
                         int* __restrict__ cnt_c, int nnz)
{
    __shared__ int hr[NSUP], hc[NSUP];
    const int tid = threadIdx.x;
    for (int i = tid; i < NSUP; i += 256) { hr[i] = 0; hc[i] = 0; }
    __syncthreads();
    for (int e = blockIdx.x * 256 + tid; e < nnz; e += gridDim.x * 256) {
        atomicAdd(&hr[rows[e] >> 9], 1);
        atomicAdd(&hc[cols[e] >> 9], 1);
    }
    __syncthreads();
    for (int i = tid; i < NSUP; i += 256) {
        if (hr[i]) atomicAdd(&cnt_r[i], hr[i]);
        if (hc[i]) atomicAdd(&cnt_c[i], hc[i]);
    }
}

// Exclusive scan of the NSUP counters (NSUP<=256). grid=2: block 0 = cols,
// block 1 = rows. Writes base[0..NSUP] (base[NSUP]=nnz) and cur[]=base[].
__global__ void scan_sup(const int* __restrict__ cnt_c, int* __restrict__ base_c,
                         int* __restrict__ cur_c,
                         const int* __restrict__ cnt_r, int* __restrict__ base_r,
                         int* __restrict__ cur_r)
{
    const int* cnt = blockIdx.x ? cnt_r : cnt_c;
    int* base = blockIdx.x ? base_r : base_c;
    int* cur  = blockIdx.x ? cur_r  : cur_c;
    __shared__ int wsum[4];
    const int lane = threadIdx.x & 63;
    const int wv = threadIdx.x >> 6;
    const int i = threadIdx.x;
    const int v = (i < NSUP) ? cnt[i] : 0;
    int incl = v;
#pragma unroll
    for (int off = 1; off < 64; off <<= 1) {
        const int t = __shfl_up(incl, off, 64);
        if (lane >= off) incl += t;
    }
    if (lane == 63) wsum[wv] = incl;
    __syncthreads();
    int woff = 0;
    for (int w = 0; w < wv; ++w) woff += wsum[w];
    const int excl = woff + incl - v;
    if (i < NSUP) { base[i] = excl; cur[i] = excl; }
    if (i == 0) base[NSUP] = wsum[0] + wsum[1] + wsum[2] + wsum[3];
}

// ---------------------------------------------------------------------------
// Level 1: group a 4096-edge chunk by super-bucket in LDS, reserve global
// space per (block, sup) with one atomic, stream grouped bursts out.
// Payload: other(17b) | keylow9 << 20.
__global__ void __launch_bounds__(256, 1)
build_l1(const int* __restrict__ key,
         const int* __restrict__ other,
         const float* __restrict__ vals,
         int* __restrict__ cursor,
         int2* __restrict__ pairs1, int nnz)
{
    __shared__ int2 stage[EPB];                  // 32 KB
    __shared__ unsigned char sg[EPB];            // 4 KB: sup of each slot
    __shared__ int hist[NSUP];
    __shared__ int sexcl[NSUP];
    __shared__ int gbase[NSUP];
    __shared__ int lcur[NSUP];
    __shared__ int wsum[4];

    const int tid = threadIdx.x;
    const int e0 = blockIdx.x * EPB;
    const int ecnt = min(EPB, nnz - e0);

    for (int i = tid; i < NSUP; i += 256) hist[i] = 0;
    __syncthreads();

    int myk[16], myo[16];
    float myv[16];
#pragma unroll
    for (int i = 0; i < 16; ++i) {
        const int s = tid + i * 256;
        if (s < ecnt) {
            const int e = e0 + s;
            myk[i] = key[e]; myo[i] = other[e]; myv[i] = vals[e];
            atomicAdd(&hist[myk[i] >> 9], 1);
        } else myk[i] = -1;
    }
    __syncthreads();

    // exclusive scan of hist (NSUP<=256), + global reservation
    {
        const int lane = tid & 63;
        const int wv = tid >> 6;
        const int v = (tid < NSUP) ? hist[tid] : 0;
        int incl = v;
#pragma unroll
        for (int off = 1; off < 64; off <<= 1) {
            const int t = __shfl_up(incl, off, 64);
            if (lane >= off) incl += t;
        }
        if (lane == 63) wsum[wv] = incl;
        __syncthreads();
        int woff = 0;
        for (int w = 0; w < wv; ++w) woff += wsum[w];
        const int excl = woff + incl - v;
        if (tid < NSUP) {
            sexcl[tid] = excl;
            lcur[tid] = excl;
            gbase[tid] = v ? atomicAdd(&cursor[tid], v) : 0;
        }
    }
    __syncthreads();

    // scatter into LDS groups
#pragma unroll
    for (int i = 0; i < 16; ++i) {
        if (myk[i] >= 0) {
            const int g = myk[i] >> 9;
            const int s = atomicAdd(&lcur[g], 1);
            stage[s] = make_int2(myo[i] | ((myk[i] & (KPS - 1)) << 20),
                                 __float_as_int(myv[i]));
            sg[s] = (unsigned char)g;
        }
    }
    __syncthreads();

    // stream out: consecutive LDS slots -> consecutive global within groups
    for (int s = tid; s < ecnt; s += 256) {
        const int g = sg[s];
        pairs1[gbase[g] + (s - sexcl[g])] = stage[s];
    }
}

// Level 2: one block per super-bucket. Exact counting sort of its region
// (~131 KB, single-CU writes -> lines fill in one L2). Emits per-key END
// offsets (global, cumulative).
__global__ void sort_l2(const int* __restrict__ base,
                        const int2* __restrict__ pairs1,
                        int2* __restrict__ pairs2,
                        int* __restrict__ fine_ends)
{
    __shared__ int cnt[KPS];                     // chunk-inclusive after scan
    __shared__ int cur[KPS];
    __shared__ int csum[8];
    const int sup = blockIdx.x;
    const int beg = base[sup];
    const int end = base[sup + 1];
    const int tid = threadIdx.x;
    const int lane = tid & 63;
    const int wv = tid >> 6;

    for (int i = tid; i < KPS; i += 256) cnt[i] = 0;
    __syncthreads();
    for (int j = beg + tid; j < end; j += 256)
        atomicAdd(&cnt[pairs1[j].x >> 20], 1);
    __syncthreads();

    // scan 512 counters: 8 chunks of 64, each wave scans 2 chunks
    int orig[2];
#pragma unroll
    for (int t = 0; t < 2; ++t) {
        const int c = wv + t * 4;
        const int v = cnt[c * 64 + lane];
        orig[t] = v;
        int incl = v;
#pragma unroll
        for (int off = 1; off < 64; off <<= 1) {
            const int u = __shfl_up(incl, off, 64);
            if (lane >= off) incl += u;
        }
        cnt[c * 64 + lane] = incl;               // chunk-local inclusive
        if (lane == 63) csum[c] = incl;
    }
    __syncthreads();
    if (tid == 0) {
        int run = 0;
#pragma unroll
        for (int c = 0; c < 8; ++c) { const int t = csum[c]; csum[c] = run; run += t; }
    }
    __syncthreads();
#pragma unroll
    for (int t = 0; t < 2; ++t) {
        const int c = wv + t * 4;
        const int i = c * 64 + lane;
        const int incl_g = csum[c] + cnt[i];     // global inclusive
        cur[i] = incl_g - orig[t];               // exclusive
        const int k = sup * KPS + i;
        if (k < N_TOTAL) fine_ends[k] = beg + incl_g;
    }
    __syncthreads();

    for (int j = beg + tid; j < end; j += 256) {
        const int2 p = pairs1[j];
        const int pos = beg + atomicAdd(&cur[p.x >> 20], 1);
        pairs2[pos] = p;                         // keep packing; pull masks
    }
}

// ---------------------------------------------------------------------------
// dst[r,:] = sum over edges of bin r: val * src[other,:]
// One wave per row; 4 edge-groups x 16 lanes x float4, unroll 4:
// 16 independent 256B gathers in flight per wave.
__global__ void spmm_pull(const int* __restrict__ ends,
                          const int2* __restrict__ pairs,
                          const float* __restrict__ src,
                          float* __restrict__ dst, int nrows)
{
    const int lane = threadIdx.x & 63;
    const int wv = threadIdx.x >> 6;
    const int r = blockIdx.x * 4 + wv;
    if (r >= nrows) return;
    const int beg = (r == 0) ? 0 : ends[r - 1];
    const int end = ends[r];
    const int g = lane >> 4;
    const int l = lane & 15;
    float4 acc = make_float4(0.f, 0.f, 0.f, 0.f);
    int j = beg + g;
    for (; j + 12 < end; j += 16) {
        const int2 p0 = pairs[j];
        const int2 p1 = pairs[j + 4];
        const int2 p2 = pairs[j + 8];
        const int2 p3 = pairs[j + 12];
        const float4 s0 = ((const float4*)(src + (size_t)(p0.x & 0xFFFFF) * EMB))[l];
        const float4 s1 = ((const float4*)(src + (size_t)(p1.x & 0xFFFFF) * EMB))[l];
        const float4 s2 = ((const float4*)(src + (size_t)(p2.x & 0xFFFFF) * EMB))[l];
        const float4 s3 = ((const float4*)(src + (size_t)(p3.x & 0xFFFFF) * EMB))[l];
        const float v0 = __int_as_float(p0.y), v1 = __int_as_float(p1.y);
        const float v2 = __int_as_float(p2.y), v3 = __int_as_float(p3.y);
        acc.x += v0 * s0.x; acc.y += v0 * s0.y; acc.z += v0 * s0.z; acc.w += v0 * s0.w;
        acc.x += v1 * s1.x; acc.y += v1 * s1.y; acc.z += v1 * s1.z; acc.w += v1 * s1.w;
        acc.x += v2 * s2.x; acc.y += v2 * s2.y; acc.z += v2 * s2.z; acc.w += v2 * s2.w;
        acc.x += v3 * s3.x; acc.y += v3 * s3.y; acc.z += v3 * s3.z; acc.w += v3 * s3.w;
    }
    for (; j < end; j += 4) {
        const int2 p = pairs[j];
        const float4 s = ((const float4*)(src + (size_t)(p.x & 0xFFFFF) * EMB))[l];
        const float v = __int_as_float(p.y);
        acc.x += v * s.x; acc.y += v * s.y; acc.z += v * s.z; acc.w += v * s.w;
    }
#pragma unroll
    for (int m = 16; m <= 32; m <<= 1) {
        acc.x += __shfl_xor(acc.x, m, 64);
        acc.y += __shfl_xor(acc.y, m, 64);
        acc.z += __shfl_xor(acc.z, m, 64);
        acc.w += __shfl_xor(acc.w, m, 64);
    }
    if (g == 0) ((float4*)(dst + (size_t)r * EMB))[l] = acc;
}

// ---------------------------------------------------------------------------
// Fallback (round-1) atomic scatter, used only if ws_size is too small.
__global__ void spmm_scatter(const int* __restrict__ src_idx,
                             const int* __restrict__ dst_idx,
                             const float* __restrict__ vals,
                             const float* __restrict__ src,
                             float* __restrict__ dst, int nnz)
{
    const long long t = (long long)blockIdx.x * blockDim.x + threadIdx.x;
    const int e = (int)(t >> 4);
    const int l = (int)(t & 15);
    if (e >= nnz) return;
    const int s = src_idx[e];
    const int d = dst_idx[e];
    const float v = vals[e];
    const float4 xv = ((const float4*)(src + (size_t)s * EMB))[l];
    float* dp = dst + (size_t)d * EMB + l * 4;
    atomicAdd(dp + 0, v * xv.x);
    atomicAdd(dp + 1, v * xv.y);
    atomicAdd(dp + 2, v * xv.z);
    atomicAdd(dp + 3, v * xv.w);
}

// ---------------------------------------------------------------------------
// out[r,:] = LN(y[r,:]) * gamma + beta + ego[r,:]
__global__ void ln_residual(const float* y,
                            const float* __restrict__ ego,
                            const float* __restrict__ gamma,
                            const float* __restrict__ beta,
                            float* out, int nrows)
{
    const int lane = threadIdx.x & 63;
    const int wave = threadIdx.x >> 6;
    const int r = blockIdx.x * 4 + wave;
    if (r >= nrows) return;
    const float v = y[(size_t)r * EMB + lane];
    float s = v, s2 = v * v;
#pragma unroll
    for (int off = 32; off > 0; off >>= 1) {
        s  += __shfl_down(s,  off, 64);
        s2 += __shfl_down(s2, off, 64);
    }
    s  = __shfl(s,  0, 64);
    s2 = __shfl(s2, 0, 64);
    const float mu  = s * (1.0f / EMB);
    const float var = s2 * (1.0f / EMB) - mu * mu;
    const float inv = rsqrtf(var + LN_EPS);
    out[(size_t)r * EMB + lane] =
        (v - mu) * inv * gamma[lane] + beta[lane] + ego[(size_t)r * EMB + lane];
}

extern "C" void kernel_launch(void* const* d_in, const int* in_sizes, int n_in,
                              void* d_out, int out_size, void* d_ws, size_t ws_size,
                              hipStream_t stream)
{
    const float* ego     = (const float*)d_in[0];
    const int*   rows    = (const int*)  d_in[1];
    const int*   cols    = (const int*)  d_in[2];
    const float* vals    = (const float*)d_in[3];
    const float* w_uu    = (const float*)d_in[4];
    const float* filt_uu = (const float*)d_in[5];
    const float* par_uu  = (const float*)d_in[6];
    const float* w_ii    = (const float*)d_in[7];
    const float* filt_ii = (const float*)d_in[8];
    const float* par_ii  = (const float*)d_in[9];
    const float* gamma   = (const float*)d_in[10];
    const float* beta    = (const float*)d_in[11];
    float* out = (float*)d_out;
    const int nnz = in_sizes[1];

    const size_t emb_elems = (size_t)N_TOTAL * EMB;
    const size_t emb_bytes = emb_elems * sizeof(float);
    float* ego2 = (float*)d_ws;                 // [0, 25.6 MB)
    float* h    = ego2 + emb_elems;             // [25.6, 51.2 MB)

    // Same bound as rounds 2/3 (proven available) — actual use is below it.
    const size_t need = 2 * emb_bytes + (size_t)nnz * sizeof(int2)
                        + 2 * (size_t)N_TOTAL * sizeof(int);

    const int rb = (N_TOTAL + 3) / 4;

    if (ws_size >= need) {
        // ---- fast path: two-level exact sort + register-accumulated pull --
        int2* pairs1    = (int2*)(h + emb_elems);         // 25.6 MB
        int*  fine_ends = (int*)(pairs1 + nnz);           // 400 KB
        int*  cnt_c  = fine_ends + N_TOTAL;               // NSUP
        int*  cnt_r  = cnt_c + NSUP;                      // NSUP
        int*  base_c = cnt_r + NSUP;                      // NSUP+1
        int*  cur_c  = base_c + (NSUP + 1);               // NSUP
        int*  base_r = cur_c + NSUP;                      // NSUP+1
        int*  cur_r  = base_r + (NSUP + 1);               // NSUP
        int2* pairs2 = (int2*)d_out;                      // 25.6 MB (dead til LN)

        hipMemsetAsync(cnt_c, 0, 2 * NSUP * sizeof(int), stream);

        hist_sup<<<512, 256, 0, stream>>>(rows, cols, cnt_r, cnt_c, nnz);
        scan_sup<<<2, 256, 0, stream>>>(cnt_c, base_c, cur_c,
                                        cnt_r, base_r, cur_r);

        transform_kernel<<<(N_USERS + 31) / 32, 256, 0, stream>>>(
            ego, w_uu, filt_uu, par_uu, ego2, N_USERS);
        transform_kernel<<<(N_ITEMS + 31) / 32, 256, 0, stream>>>(
            ego + (size_t)N_USERS * EMB, w_ii, filt_ii, par_ii,
            ego2 + (size_t)N_USERS * EMB, N_ITEMS);

        const int l1b = (nnz + EPB - 1) / EPB;

        // Pass 1: key = col, payload = row.  h[c] = sum val*ego2[r]
        build_l1<<<l1b, 256, 0, stream>>>(cols, rows, vals, cur_c, pairs1, nnz);
        sort_l2<<<NSUP, 256, 0, stream>>>(base_c, pairs1, pairs2, fine_ends);
        spmm_pull<<<rb, 256, 0, stream>>>(fine_ends, pairs2, ego2, h, N_TOTAL);

        // Pass 2: key = row, payload = col.  y[r] = sum val*h[c] -> ego2
        build_l1<<<l1b, 256, 0, stream>>>(rows, cols, vals, cur_r, pairs1, nnz);
        sort_l2<<<NSUP, 256, 0, stream>>>(base_r, pairs1, pairs2, fine_ends);
        spmm_pull<<<rb, 256, 0, stream>>>(fine_ends, pairs2, h, ego2, N_TOTAL);

        // LN + residual: read y from ego2, write all of d_out (frees pairs2).
        ln_residual<<<rb, 256, 0, stream>>>(ego2, ego, gamma, beta, out, N_TOTAL);
    } else {
        // ---------------- fallback: atomic scatter (round-1) -------------
        hipMemsetAsync(h,   0, emb_bytes, stream);
        hipMemsetAsync(out, 0, emb_bytes, stream);

        transform_kernel<<<(N_USERS + 31) / 32, 256, 0, stream>>>(
            ego, w_uu, filt_uu, par_uu, ego2, N_USERS);
        transform_kernel<<<(N_ITEMS + 31) / 32, 256, 0, stream>>>(
            ego + (size_t)N_USERS * EMB, w_ii, filt_ii, par_ii,
            ego2 + (size_t)N_USERS * EMB, N_ITEMS);

        const long long thr = (long long)nnz * 16;
        const int sblocks = (int)((thr + 255) / 256);
        spmm_scatter<<<sblocks, 256, 0, stream>>>(rows, cols, vals, ego2, h, nnz);
        spmm_scatter<<<sblocks, 256, 0, stream>>>(cols, rows, vals, h, out, nnz);

        ln_residual<<<rb, 256, 0, stream>>>(out, ego, gamma, beta, out, N_TOTAL);
    }
}

// Round 6
// 541.138 us; speedup vs baseline: 5.9566x; 1.1733x over previous
//
#include <hip/hip_runtime.h>

#define N_USERS 60000
#define N_ITEMS 40000
#define N_TOTAL 100000
#define EMB 64
#define LN_EPS 1e-5f

#define KPS 512                                  // keys per super-bucket
#define NSUP ((N_TOTAL + KPS - 1) / KPS)         // 196
#define EPB 4096                                 // edges per build_l1 block

// bf16 helpers (exact shift for bf16->f32; RNE for f32->bf16)
__device__ __forceinline__ float bf2f(unsigned short h)
{ return __uint_as_float(((unsigned)h) << 16); }
__device__ __forceinline__ unsigned short f2bf(float f)
{
    unsigned u = __float_as_uint(f);
    return (unsigned short)((u + 0x7FFFu + ((u >> 16) & 1u)) >> 16);
}

// ---------------------------------------------------------------------------
// ego2[r,:] = c * filt[r] * (x[r,:] @ W) + x[r,:]   (bf16 output)
// One kernel for users+items: both W's staged in LDS, per-row select.
__global__ void transform_all(const float* __restrict__ x,
                              const float* __restrict__ w_uu,
                              const float* __restrict__ filt_uu,
                              const float* __restrict__ par_uu,
                              const float* __restrict__ w_ii,
                              const float* __restrict__ filt_ii,
                              const float* __restrict__ par_ii,
                              unsigned short* __restrict__ out)
{
    __shared__ float Ws[2][EMB * EMB];           // 32 KB
    const int tid = threadIdx.x;
    for (int i = tid; i < EMB * EMB; i += 256) {
        Ws[0][i] = w_uu[i];
        Ws[1][i] = w_ii[i];
    }
    __syncthreads();
    const float c_uu = par_uu[0] * par_uu[1];
    const float c_ii = par_ii[0] * par_ii[1];
    const int lane = tid & 63;
    const int wave = tid >> 6;
    const int r0 = blockIdx.x * 32;
    for (int rr = wave; rr < 32; rr += 4) {
        const int r = r0 + rr;
        if (r >= N_TOTAL) break;
        const int itm = (r >= N_USERS);
        const float cf = itm ? c_ii * filt_ii[r - N_USERS] : c_uu * filt_uu[r];
        const float* W = Ws[itm];
        const float xv = x[(size_t)r * EMB + lane];
        float acc = 0.f;
#pragma unroll
        for (int k = 0; k < EMB; ++k) {
            const float xk = __shfl(xv, k, 64);
            acc += xk * W[k * EMB + lane];
        }
        out[(size_t)r * EMB + lane] = f2bf(cf * acc + xv);
    }
}

// ---------------------------------------------------------------------------
// Super-bucket histograms for BOTH orderings. LDS-local then merge.
__global__ void hist_sup(const int* __restrict__ rows,
                         const int* __restrict__ cols,
                         int* __restrict__ cnt_r,
                         int* __restrict__ cnt_c, int nnz)
{
    __shared__ int hr[NSUP], hc[NSUP];
    const int tid = threadIdx.x;
    for (int i = tid; i < NSUP; i += 256) { hr[i] = 0; hc[i] = 0; }
    __syncthreads();
    for (int e = blockIdx.x * 256 + tid; e < nnz; e += gridDim.x * 256) {
        atomicAdd(&hr[rows[e] >> 9], 1);
        atomicAdd(&hc[cols[e] >> 9], 1);
    }
    __syncthreads();
    for (int i = tid; i < NSUP; i += 256) {
        if (hr[i]) atomicAdd(&cnt_r[i], hr[i]);
        if (hc[i]) atomicAdd(&cnt_c[i], hc[i]);
    }
}

// Exclusive scan of the NSUP counters. grid=2: block 0 = cols, 1 = rows.
__global__ void scan_sup(const int* __restrict__ cnt_c, int* __restrict__ base_c,
                         int* __restrict__ cur_c,
                         const int* __restrict__ cnt_r, int* __restrict__ base_r,
                         int* __restrict__ cur_r)
{
    const int* cnt = blockIdx.x ? cnt_r : cnt_c;
    int* base = blockIdx.x ? base_r : base_c;
    int* cur  = blockIdx.x ? cur_r  : cur_c;
    __shared__ int wsum[4];
    const int lane = threadIdx.x & 63;
    const int wv = threadIdx.x >> 6;
    const int i = threadIdx.x;
    const int v = (i < NSUP) ? cnt[i] : 0;
    int incl = v;
#pragma unroll
    for (int off = 1; off < 64; off <<= 1) {
        const int t = __shfl_up(incl, off, 64);
        if (lane >= off) incl += t;
    }
    if (lane == 63) wsum[wv] = incl;
    __syncthreads();
    int woff = 0;
    for (int w = 0; w < wv; ++w) woff += wsum[w];
    const int excl = woff + incl - v;
    if (i < NSUP) { base[i] = excl; cur[i] = excl; }
    if (i == 0) base[NSUP] = wsum[0] + wsum[1] + wsum[2] + wsum[3];
}

// ---------------------------------------------------------------------------
// Level 1: group a 4096-edge chunk by super-bucket in LDS, reserve global
// space per (block, sup) with one atomic, stream grouped bursts out.
// Payload: other(17b) | keylow9 << 20.
__global__ void __launch_bounds__(256, 1)
build_l1(const int* __restrict__ key,
         const int* __restrict__ other,
         const float* __restrict__ vals,
         int* __restrict__ cursor,
         int2* __restrict__ pairs1, int nnz)
{
    __shared__ int2 stage[EPB];                  // 32 KB
    __shared__ unsigned char sg[EPB];            // 4 KB
    __shared__ int hist[NSUP];
    __shared__ int sexcl[NSUP];
    __shared__ int gbase[NSUP];
    __shared__ int lcur[NSUP];
    __shared__ int wsum[4];

    const int tid = threadIdx.x;
    const int e0 = blockIdx.x * EPB;
    const int ecnt = min(EPB, nnz - e0);

    for (int i = tid; i < NSUP; i += 256) hist[i] = 0;
    __syncthreads();

    int myk[16], myo[16];
    float myv[16];
#pragma unroll
    for (int i = 0; i < 16; ++i) {
        const int s = tid + i * 256;
        if (s < ecnt) {
            const int e = e0 + s;
            myk[i] = key[e]; myo[i] = other[e]; myv[i] = vals[e];
            atomicAdd(&hist[myk[i] >> 9], 1);
        } else myk[i] = -1;
    }
    __syncthreads();

    {
        const int lane = tid & 63;
        const int wv = tid >> 6;
        const int v = (tid < NSUP) ? hist[tid] : 0;
        int incl = v;
#pragma unroll
        for (int off = 1; off < 64; off <<= 1) {
            const int t = __shfl_up(incl, off, 64);
            if (lane >= off) incl += t;
        }
        if (lane == 63) wsum[wv] = incl;
        __syncthreads();
        int woff = 0;
        for (int w = 0; w < wv; ++w) woff += wsum[w];
        const int excl = woff + incl - v;
        if (tid < NSUP) {
            sexcl[tid] = excl;
            lcur[tid] = excl;
            gbase[tid] = v ? atomicAdd(&cursor[tid], v) : 0;
        }
    }
    __syncthreads();

#pragma unroll
    for (int i = 0; i < 16; ++i) {
        if (myk[i] >= 0) {
            const int g = myk[i] >> 9;
            const int s = atomicAdd(&lcur[g], 1);
            stage[s] = make_int2(myo[i] | ((myk[i] & (KPS - 1)) << 20),
                                 __float_as_int(myv[i]));
            sg[s] = (unsigned char)g;
        }
    }
    __syncthreads();

    for (int s = tid; s < ecnt; s += 256) {
        const int g = sg[s];
        pairs1[gbase[g] + (s - sexcl[g])] = stage[s];
    }
}

// Level 2: one block per super-bucket. Exact counting sort of its region.
// Emits per-key END offsets (global, cumulative).
__global__ void sort_l2(const int* __restrict__ base,
                        const int2* __restrict__ pairs1,
                        int2* __restrict__ pairs2,
                        int* __restrict__ fine_ends)
{
    __shared__ int cnt[KPS];
    __shared__ int cur[KPS];
    __shared__ int csum[8];
    const int sup = blockIdx.x;
    const int beg = base[sup];
    const int end = base[sup + 1];
    const int tid = threadIdx.x;
    const int lane = tid & 63;
    const int wv = tid >> 6;

    for (int i = tid; i < KPS; i += 256) cnt[i] = 0;
    __syncthreads();
    for (int j = beg + tid; j < end; j += 256)
        atomicAdd(&cnt[pairs1[j].x >> 20], 1);
    __syncthreads();

    int orig[2];
#pragma unroll
    for (int t = 0; t < 2; ++t) {
        const int c = wv + t * 4;
        const int v = cnt[c * 64 + lane];
        orig[t] = v;
        int incl = v;
#pragma unroll
        for (int off = 1; off < 64; off <<= 1) {
            const int u = __shfl_up(incl, off, 64);
            if (lane >= off) incl += u;
        }
        cnt[c * 64 + lane] = incl;
        if (lane == 63) csum[c] = incl;
    }
    __syncthreads();
    if (tid == 0) {
        int run = 0;
#pragma unroll
        for (int c = 0; c < 8; ++c) { const int t = csum[c]; csum[c] = run; run += t; }
    }
    __syncthreads();
#pragma unroll
    for (int t = 0; t < 2; ++t) {
        const int c = wv + t * 4;
        const int i = c * 64 + lane;
        const int incl_g = csum[c] + cnt[i];
        cur[i] = incl_g - orig[t];
        const int k = sup * KPS + i;
        if (k < N_TOTAL) fine_ends[k] = beg + incl_g;
    }
    __syncthreads();

    for (int j = beg + tid; j < end; j += 256) {
        const int2 p = pairs1[j];
        const int pos = beg + atomicAdd(&cur[p.x >> 20], 1);
        pairs2[pos] = p;
    }
}

// ---------------------------------------------------------------------------
// dst[r,:] = sum over edges of bin r: val * src[other,:]
// src in bf16 (row = 128 B). 4 edge-groups x 16 lanes x bf16x4; unroll 4.
// DST = unsigned short (bf16 out, pass 1) or float (fp32 out, pass 2).
template <typename DST>
__global__ void spmm_pull_bf16(const int* __restrict__ ends,
                               const int2* __restrict__ pairs,
                               const unsigned short* __restrict__ src,
                               DST* __restrict__ dst, int nrows)
{
    const int lane = threadIdx.x & 63;
    const int wv = threadIdx.x >> 6;
    const int r = blockIdx.x * 4 + wv;
    if (r >= nrows) return;
    const int beg = (r == 0) ? 0 : ends[r - 1];
    const int end = ends[r];
    const int g = lane >> 4;
    const int l = lane & 15;
    float4 acc = make_float4(0.f, 0.f, 0.f, 0.f);
    int j = beg + g;
    for (; j + 12 < end; j += 16) {
        const int2 p0 = pairs[j];
        const int2 p1 = pairs[j + 4];
        const int2 p2 = pairs[j + 8];
        const int2 p3 = pairs[j + 12];
        const ushort4 s0 = ((const ushort4*)(src + (size_t)(p0.x & 0xFFFFF) * EMB))[l];
        const ushort4 s1 = ((const ushort4*)(src + (size_t)(p1.x & 0xFFFFF) * EMB))[l];
        const ushort4 s2 = ((const ushort4*)(src + (size_t)(p2.x & 0xFFFFF) * EMB))[l];
        const ushort4 s3 = ((const ushort4*)(src + (size_t)(p3.x & 0xFFFFF) * EMB))[l];
        const float v0 = __int_as_float(p0.y), v1 = __int_as_float(p1.y);
        const float v2 = __int_as_float(p2.y), v3 = __int_as_float(p3.y);
        acc.x += v0 * bf2f(s0.x); acc.y += v0 * bf2f(s0.y);
        acc.z += v0 * bf2f(s0.z); acc.w += v0 * bf2f(s0.w);
        acc.x += v1 * bf2f(s1.x); acc.y += v1 * bf2f(s1.y);
        acc.z += v1 * bf2f(s1.z); acc.w += v1 * bf2f(s1.w);
        acc.x += v2 * bf2f(s2.x); acc.y += v2 * bf2f(s2.y);
        acc.z += v2 * bf2f(s2.z); acc.w += v2 * bf2f(s2.w);
        acc.x += v3 * bf2f(s3.x); acc.y += v3 * bf2f(s3.y);
        acc.z += v3 * bf2f(s3.z); acc.w += v3 * bf2f(s3.w);
    }
    for (; j < end; j += 4) {
        const int2 p = pairs[j];
        const ushort4 s = ((const ushort4*)(src + (size_t)(p.x & 0xFFFFF) * EMB))[l];
        const float v = __int_as_float(p.y);
        acc.x += v * bf2f(s.x); acc.y += v * bf2f(s.y);
        acc.z += v * bf2f(s.z); acc.w += v * bf2f(s.w);
    }
#pragma unroll
    for (int m = 16; m <= 32; m <<= 1) {
        acc.x += __shfl_xor(acc.x, m, 64);
        acc.y += __shfl_xor(acc.y, m, 64);
        acc.z += __shfl_xor(acc.z, m, 64);
        acc.w += __shfl_xor(acc.w, m, 64);
    }
    if (g == 0) {
        if constexpr (sizeof(DST) == 2) {
            ushort4 o;
            o.x = f2bf(acc.x); o.y = f2bf(acc.y);
            o.z = f2bf(acc.z); o.w = f2bf(acc.w);
            ((ushort4*)(dst + (size_t)r * EMB))[l] = o;
        } else {
            ((float4*)(dst + (size_t)r * EMB))[l] = acc;
        }
    }
}

// ---------------------------------------------------------------------------
// Fallback (round-1) atomic scatter path, fp32, used only if ws too small.
__global__ void transform_kernel(const float* __restrict__ x,
                                 const float* __restrict__ W,
                                 const float* __restrict__ filt,
                                 const float* __restrict__ par,
                                 float* __restrict__ out, int nrows)
{
    __shared__ float Ws[EMB * EMB];
    const int tid = threadIdx.x;
    for (int i = tid; i < EMB * EMB; i += blockDim.x) Ws[i] = W[i];
    __syncthreads();
    const float c = par[0] * par[1];
    const int lane = tid & 63;
    const int wave = tid >> 6;
    const int r0 = blockIdx.x * 32;
    for (int rr = wave; rr < 32; rr += 4) {
        const int r = r0 + rr;
        if (r >= nrows) break;
        const float xv = x[(size_t)r * EMB + lane];
        float acc = 0.f;
#pragma unroll
        for (int k = 0; k < EMB; ++k) {
            const float xk = __shfl(xv, k, 64);
            acc += xk * Ws[k * EMB + lane];
        }
        out[(size_t)r * EMB + lane] = c * filt[r] * acc + xv;
    }
}

__global__ void spmm_scatter(const int* __restrict__ src_idx,
                             const int* __restrict__ dst_idx,
                             const float* __restrict__ vals,
                             const float* __restrict__ src,
                             float* __restrict__ dst, int nnz)
{
    const long long t = (long long)blockIdx.x * blockDim.x + threadIdx.x;
    const int e = (int)(t >> 4);
    const int l = (int)(t & 15);
    if (e >= nnz) return;
    const int s = src_idx[e];
    const int d = dst_idx[e];
    const float v = vals[e];
    const float4 xv = ((const float4*)(src + (size_t)s * EMB))[l];
    float* dp = dst + (size_t)d * EMB + l * 4;
    atomicAdd(dp + 0, v * xv.x);
    atomicAdd(dp + 1, v * xv.y);
    atomicAdd(dp + 2, v * xv.z);
    atomicAdd(dp + 3, v * xv.w);
}

// ---------------------------------------------------------------------------
// out[r,:] = LN(y[r,:]) * gamma + beta + ego[r,:]
__global__ void ln_residual(const float* y,
                            const float* __restrict__ ego,
                            const float* __restrict__ gamma,
                            const float* __restrict__ beta,
                            float* out, int nrows)
{
    const int lane = threadIdx.x & 63;
    const int wave = threadIdx.x >> 6;
    const int r = blockIdx.x * 4 + wave;
    if (r >= nrows) return;
    const float v = y[(size_t)r * EMB + lane];
    float s = v, s2 = v * v;
#pragma unroll
    for (int off = 32; off > 0; off >>= 1) {
        s  += __shfl_down(s,  off, 64);
        s2 += __shfl_down(s2, off, 64);
    }
    s  = __shfl(s,  0, 64);
    s2 = __shfl(s2, 0, 64);
    const float mu  = s * (1.0f / EMB);
    const float var = s2 * (1.0f / EMB) - mu * mu;
    const float inv = rsqrtf(var + LN_EPS);
    out[(size_t)r * EMB + lane] =
        (v - mu) * inv * gamma[lane] + beta[lane] + ego[(size_t)r * EMB + lane];
}

extern "C" void kernel_launch(void* const* d_in, const int* in_sizes, int n_in,
                              void* d_out, int out_size, void* d_ws, size_t ws_size,
                              hipStream_t stream)
{
    const float* ego     = (const float*)d_in[0];
    const int*   rows    = (const int*)  d_in[1];
    const int*   cols    = (const int*)  d_in[2];
    const float* vals    = (const float*)d_in[3];
    const float* w_uu    = (const float*)d_in[4];
    const float* filt_uu = (const float*)d_in[5];
    const float* par_uu  = (const float*)d_in[6];
    const float* w_ii    = (const float*)d_in[7];
    const float* filt_ii = (const float*)d_in[8];
    const float* par_ii  = (const float*)d_in[9];
    const float* gamma   = (const float*)d_in[10];
    const float* beta    = (const float*)d_in[11];
    float* out = (float*)d_out;
    const int nnz = in_sizes[1];

    const size_t emb_elems = (size_t)N_TOTAL * EMB;
    const size_t emb_bytes = emb_elems * sizeof(float);

    // Same bound as rounds 2-5 (proven available); actual use fits under it.
    const size_t need = 2 * emb_bytes + (size_t)nnz * sizeof(int2)
                        + 2 * (size_t)N_TOTAL * sizeof(int);

    const int rb = (N_TOTAL + 3) / 4;

    if (ws_size >= need) {
        // ---- fast path: two-level exact sort + bf16 register pull --------
        unsigned short* ego2b = (unsigned short*)d_ws;    // 12.8 MB
        unsigned short* hb    = ego2b + emb_elems;        // 12.8 MB
        float* y              = (float*)(hb + emb_elems); // 25.6 MB
        int2*  pairs1    = (int2*)(y + emb_elems);        // 25.6 MB
        int*   fine_ends = (int*)(pairs1 + nnz);          // 400 KB
        int*   cnt_c  = fine_ends + N_TOTAL;
        int*   cnt_r  = cnt_c + NSUP;
        int*   base_c = cnt_r + NSUP;
        int*   cur_c  = base_c + (NSUP + 1);
        int*   base_r = cur_c + NSUP;
        int*   cur_r  = base_r + (NSUP + 1);
        int2*  pairs2 = (int2*)d_out;                     // 25.6 MB (dead til LN)

        hipMemsetAsync(cnt_c, 0, 2 * NSUP * sizeof(int), stream);

        hist_sup<<<512, 256, 0, stream>>>(rows, cols, cnt_r, cnt_c, nnz);
        scan_sup<<<2, 256, 0, stream>>>(cnt_c, base_c, cur_c,
                                        cnt_r, base_r, cur_r);

        transform_all<<<(N_TOTAL + 31) / 32, 256, 0, stream>>>(
            ego, w_uu, filt_uu, par_uu, w_ii, filt_ii, par_ii, ego2b);

        const int l1b = (nnz + EPB - 1) / EPB;

        // Pass 1: key = col, payload = row.  h[c] = sum val*ego2[r]  (bf16)
        build_l1<<<l1b, 256, 0, stream>>>(cols, rows, vals, cur_c, pairs1, nnz);
        sort_l2<<<NSUP, 256, 0, stream>>>(base_c, pairs1, pairs2, fine_ends);
        spmm_pull_bf16<unsigned short><<<rb, 256, 0, stream>>>(
            fine_ends, pairs2, ego2b, hb, N_TOTAL);

        // Pass 2: key = row, payload = col.  y[r] = sum val*h[c]  (fp32)
        build_l1<<<l1b, 256, 0, stream>>>(rows, cols, vals, cur_r, pairs1, nnz);
        sort_l2<<<NSUP, 256, 0, stream>>>(base_r, pairs1, pairs2, fine_ends);
        spmm_pull_bf16<float><<<rb, 256, 0, stream>>>(
            fine_ends, pairs2, hb, y, N_TOTAL);

        // LN + residual: read y, write all of d_out (frees pairs2).
        ln_residual<<<rb, 256, 0, stream>>>(y, ego, gamma, beta, out, N_TOTAL);
    } else {
        // ---------------- fallback: atomic scatter (round-1, fp32) -------
        float* ego2 = (float*)d_ws;
        float* h    = ego2 + emb_elems;
        hipMemsetAsync(h,   0, emb_bytes, stream);
        hipMemsetAsync(out, 0, emb_bytes, stream);

        transform_kernel<<<(N_USERS + 31) / 32, 256, 0, stream>>>(
            ego, w_uu, filt_uu, par_uu, ego2, N_USERS);
        transform_kernel<<<(N_ITEMS + 31) / 32, 256, 0, stream>>>(
            ego + (size_t)N_USERS * EMB, w_ii, filt_ii, par_ii,
            ego2 + (size_t)N_USERS * EMB, N_ITEMS);

        const long long thr = (long long)nnz * 16;
        const int sblocks = (int)((thr + 255) / 256);
        spmm_scatter<<<sblocks, 256, 0, stream>>>(rows, cols, vals, ego2, h, nnz);
        spmm_scatter<<<sblocks, 256, 0, stream>>>(cols, rows, vals, h, out, nnz);

        ln_residual<<<rb, 256, 0, stream>>>(out, ego, gamma, beta, out, N_TOTAL);
    }
}

// Round 7
// 459.127 us; speedup vs baseline: 7.0206x; 1.1786x over previous
//
#include <hip/hip_runtime.h>

#define N_USERS 60000
#define N_ITEMS 40000
#define N_TOTAL 100000
#define EMB 64
#define LN_EPS 1e-5f

#define KPS 512                                  // keys per super-bucket
#define NSUP ((N_TOTAL + KPS - 1) / KPS)         // 196
#define EPB 4096                                 // edges per build_l1 block
#define TR_ROWS 32                               // rows per transform block
#define XPITCH 68                                // x-tile pitch (floats): banks
                                                 // differ per row, 16B-aligned

// bf16 helpers (exact shift for bf16->f32; RNE for f32->bf16)
__device__ __forceinline__ float bf2f(unsigned short h)
{ return __uint_as_float(((unsigned)h) << 16); }
__device__ __forceinline__ unsigned short f2bf(float f)
{
    unsigned u = __float_as_uint(f);
    return (unsigned short)((u + 0x7FFFu + ((u >> 16) & 1u)) >> 16);
}

// ---------------------------------------------------------------------------
// ego2[r,:] = c * filt[r] * (x[r,:] @ W) + x[r,:]   (bf16 output)
// Tiled: W fp32 in LDS (block-uniform type: 60000 % TR_ROWS == 0), 32-row
// x-tile in LDS at pitch 68. Wave-iter = 4 rows x 64 cols; lane =
// (rowgroup rg, colgroup j): per k one broadcast ds_read_b32 (x) + one
// ds_read_b128 (W cols 4j..4j+3) + 4 FMA. No shfl in the hot loop.
__global__ void transform_tile(const float* __restrict__ x,
                               const float* __restrict__ w_uu,
                               const float* __restrict__ filt_uu,
                               const float* __restrict__ par_uu,
                               const float* __restrict__ w_ii,
                               const float* __restrict__ filt_ii,
                               const float* __restrict__ par_ii,
                               unsigned short* __restrict__ out)
{
    __shared__ float Wls[EMB * EMB];             // 16 KB
    __shared__ float xs[TR_ROWS * XPITCH];       // 8.7 KB
    const int tid = threadIdx.x;
    const int r0 = blockIdx.x * TR_ROWS;
    const int itm = (r0 >= N_USERS);             // uniform per block
    const float* W  = itm ? w_ii : w_uu;
    const float* fb = itm ? filt_ii : filt_uu;
    const int foff  = itm ? N_USERS : 0;
    const float c   = itm ? par_ii[0] * par_ii[1] : par_uu[0] * par_uu[1];

    // stage W (1024 float4) and x-tile (512 float4)
    for (int i = tid; i < EMB * EMB / 4; i += 256)
        ((float4*)Wls)[i] = ((const float4*)W)[i];
    for (int i = tid; i < TR_ROWS * 16; i += 256) {
        const float4 v = ((const float4*)x)[r0 * 16 + i];
        *(float4*)&xs[(i >> 4) * XPITCH + (i & 15) * 4] = v;
    }
    __syncthreads();

    const int lane = tid & 63;
    const int wv = tid >> 6;
    const int rg = lane >> 4;                    // row within quad
    const int j  = lane & 15;                    // col group (4 cols)

#pragma unroll
    for (int it = 0; it < 2; ++it) {
        const int rl = wv * 8 + it * 4 + rg;     // local row 0..31
        const int row = r0 + rl;
        float4 acc = make_float4(0.f, 0.f, 0.f, 0.f);
#pragma unroll 8
        for (int k = 0; k < EMB; ++k) {
            const float xb = xs[rl * XPITCH + k];
            const float4 w4 = *(const float4*)&Wls[k * EMB + 4 * j];
            acc.x += xb * w4.x; acc.y += xb * w4.y;
            acc.z += xb * w4.z; acc.w += xb * w4.w;
        }
        const float cf = c * fb[row - foff];
        const float4 xv = *(const float4*)&xs[rl * XPITCH + 4 * j];
        ushort4 o;
        o.x = f2bf(cf * acc.x + xv.x);
        o.y = f2bf(cf * acc.y + xv.y);
        o.z = f2bf(cf * acc.z + xv.z);
        o.w = f2bf(cf * acc.w + xv.w);
        *(ushort4*)&out[(size_t)row * EMB + 4 * j] = o;
    }
}

// ---------------------------------------------------------------------------
// Super-bucket histograms for BOTH orderings. LDS-local then merge.
__global__ void hist_sup(const int* __restrict__ rows,
                         const int* __restrict__ cols,
                         int* __restrict__ cnt_r,
                         int* __restrict__ cnt_c, int nnz)
{
    __shared__ int hr[NSUP], hc[NSUP];
    const int tid = threadIdx.x;
    for (int i = tid; i < NSUP; i += 256) { hr[i] = 0; hc[i] = 0; }
    __syncthreads();
    for (int e = blockIdx.x * 256 + tid; e < nnz; e += gridDim.x * 256) {
        atomicAdd(&hr[rows[e] >> 9], 1);
        atomicAdd(&hc[cols[e] >> 9], 1);
    }
    __syncthreads();
    for (int i = tid; i < NSUP; i += 256) {
        if (hr[i]) atomicAdd(&cnt_r[i], hr[i]);
        if (hc[i]) atomicAdd(&cnt_c[i], hc[i]);
    }
}

// Exclusive scan of the NSUP counters. grid=2: block 0 = cols, 1 = rows.
__global__ void scan_sup(const int* __restrict__ cnt_c, int* __restrict__ base_c,
                         int* __restrict__ cur_c,
                         const int* __restrict__ cnt_r, int* __restrict__ base_r,
                         int* __restrict__ cur_r)
{
    const int* cnt = blockIdx.x ? cnt_r : cnt_c;
    int* base = blockIdx.x ? base_r : base_c;
    int* cur  = blockIdx.x ? cur_r  : cur_c;
    __shared__ int wsum[4];
    const int lane = threadIdx.x & 63;
    const int wv = threadIdx.x >> 6;
    const int i = threadIdx.x;
    const int v = (i < NSUP) ? cnt[i] : 0;
    int incl = v;
#pragma unroll
    for (int off = 1; off < 64; off <<= 1) {
        const int t = __shfl_up(incl, off, 64);
        if (lane >= off) incl += t;
    }
    if (lane == 63) wsum[wv] = incl;
    __syncthreads();
    int woff = 0;
    for (int w = 0; w < wv; ++w) woff += wsum[w];
    const int excl = woff + incl - v;
    if (i < NSUP) { base[i] = excl; cur[i] = excl; }
    if (i == 0) base[NSUP] = wsum[0] + wsum[1] + wsum[2] + wsum[3];
}

// ---------------------------------------------------------------------------
// Level 1: group a 4096-edge chunk by super-bucket in LDS, reserve global
// space per (block, sup) with one atomic, stream grouped bursts out.
// Payload: other(17b) | keylow9 << 20.
__global__ void __launch_bounds__(256, 1)
build_l1(const int* __restrict__ key,
         const int* __restrict__ other,
         const float* __restrict__ vals,
         int* __restrict__ cursor,
         int2* __restrict__ pairs1, int nnz)
{
    __shared__ int2 stage[EPB];                  // 32 KB
    __shared__ unsigned char sg[EPB];            // 4 KB
    __shared__ int hist[NSUP];
    __shared__ int sexcl[NSUP];
    __shared__ int gbase[NSUP];
    __shared__ int lcur[NSUP];
    __shared__ int wsum[4];

    const int tid = threadIdx.x;
    const int e0 = blockIdx.x * EPB;
    const int ecnt = min(EPB, nnz - e0);

    for (int i = tid; i < NSUP; i += 256) hist[i] = 0;
    __syncthreads();

    int myk[16], myo[16];
    float myv[16];
#pragma unroll
    for (int i = 0; i < 16; ++i) {
        const int s = tid + i * 256;
        if (s < ecnt) {
            const int e = e0 + s;
            myk[i] = key[e]; myo[i] = other[e]; myv[i] = vals[e];
            atomicAdd(&hist[myk[i] >> 9], 1);
        } else myk[i] = -1;
    }
    __syncthreads();

    {
        const int lane = tid & 63;
        const int wv = tid >> 6;
        const int v = (tid < NSUP) ? hist[tid] : 0;
        int incl = v;
#pragma unroll
        for (int off = 1; off < 64; off <<= 1) {
            const int t = __shfl_up(incl, off, 64);
            if (lane >= off) incl += t;
        }
        if (lane == 63) wsum[wv] = incl;
        __syncthreads();
        int woff = 0;
        for (int w = 0; w < wv; ++w) woff += wsum[w];
        const int excl = woff + incl - v;
        if (tid < NSUP) {
            sexcl[tid] = excl;
            lcur[tid] = excl;
            gbase[tid] = v ? atomicAdd(&cursor[tid], v) : 0;
        }
    }
    __syncthreads();

#pragma unroll
    for (int i = 0; i < 16; ++i) {
        if (myk[i] >= 0) {
            const int g = myk[i] >> 9;
            const int s = atomicAdd(&lcur[g], 1);
            stage[s] = make_int2(myo[i] | ((myk[i] & (KPS - 1)) << 20),
                                 __float_as_int(myv[i]));
            sg[s] = (unsigned char)g;
        }
    }
    __syncthreads();

    for (int s = tid; s < ecnt; s += 256) {
        const int g = sg[s];
        pairs1[gbase[g] + (s - sexcl[g])] = stage[s];
    }
}

// Level 2: one block per super-bucket. Exact counting sort of its region.
// Emits per-key END offsets (global, cumulative).
__global__ void sort_l2(const int* __restrict__ base,
                        const int2* __restrict__ pairs1,
                        int2* __restrict__ pairs2,
                        int* __restrict__ fine_ends)
{
    __shared__ int cnt[KPS];
    __shared__ int cur[KPS];
    __shared__ int csum[8];
    const int sup = blockIdx.x;
    const int beg = base[sup];
    const int end = base[sup + 1];
    const int tid = threadIdx.x;
    const int lane = tid & 63;
    const int wv = tid >> 6;

    for (int i = tid; i < KPS; i += 256) cnt[i] = 0;
    __syncthreads();
    for (int j = beg + tid; j < end; j += 256)
        atomicAdd(&cnt[pairs1[j].x >> 20], 1);
    __syncthreads();

    int orig[2];
#pragma unroll
    for (int t = 0; t < 2; ++t) {
        const int c = wv + t * 4;
        const int v = cnt[c * 64 + lane];
        orig[t] = v;
        int incl = v;
#pragma unroll
        for (int off = 1; off < 64; off <<= 1) {
            const int u = __shfl_up(incl, off, 64);
            if (lane >= off) incl += u;
        }
        cnt[c * 64 + lane] = incl;
        if (lane == 63) csum[c] = incl;
    }
    __syncthreads();
    if (tid == 0) {
        int run = 0;
#pragma unroll
        for (int c = 0; c < 8; ++c) { const int t = csum[c]; csum[c] = run; run += t; }
    }
    __syncthreads();
#pragma unroll
    for (int t = 0; t < 2; ++t) {
        const int c = wv + t * 4;
        const int i = c * 64 + lane;
        const int incl_g = csum[c] + cnt[i];
        cur[i] = incl_g - orig[t];
        const int k = sup * KPS + i;
        if (k < N_TOTAL) fine_ends[k] = beg + incl_g;
    }
    __syncthreads();

    for (int j = beg + tid; j < end; j += 256) {
        const int2 p = pairs1[j];
        const int pos = beg + atomicAdd(&cur[p.x >> 20], 1);
        pairs2[pos] = p;
    }
}

// ---------------------------------------------------------------------------
// Pass 1: dst bf16. 4 edge-groups x 16 lanes x bf16x4; unroll 4.
__global__ void spmm_pull_bf16(const int* __restrict__ ends,
                               const int2* __restrict__ pairs,
                               const unsigned short* __restrict__ src,
                               unsigned short* __restrict__ dst, int nrows)
{
    const int lane = threadIdx.x & 63;
    const int wv = threadIdx.x >> 6;
    const int r = blockIdx.x * 4 + wv;
    if (r >= nrows) return;
    const int beg = (r == 0) ? 0 : ends[r - 1];
    const int end = ends[r];
    const int g = lane >> 4;
    const int l = lane & 15;
    float4 acc = make_float4(0.f, 0.f, 0.f, 0.f);
    int j = beg + g;
    for (; j + 12 < end; j += 16) {
        const int2 p0 = pairs[j];
        const int2 p1 = pairs[j + 4];
        const int2 p2 = pairs[j + 8];
        const int2 p3 = pairs[j + 12];
        const ushort4 s0 = ((const ushort4*)(src + (size_t)(p0.x & 0xFFFFF) * EMB))[l];
        const ushort4 s1 = ((const ushort4*)(src + (size_t)(p1.x & 0xFFFFF) * EMB))[l];
        const ushort4 s2 = ((const ushort4*)(src + (size_t)(p2.x & 0xFFFFF) * EMB))[l];
        const ushort4 s3 = ((const ushort4*)(src + (size_t)(p3.x & 0xFFFFF) * EMB))[l];
        const float v0 = __int_as_float(p0.y), v1 = __int_as_float(p1.y);
        const float v2 = __int_as_float(p2.y), v3 = __int_as_float(p3.y);
        acc.x += v0 * bf2f(s0.x); acc.y += v0 * bf2f(s0.y);
        acc.z += v0 * bf2f(s0.z); acc.w += v0 * bf2f(s0.w);
        acc.x += v1 * bf2f(s1.x); acc.y += v1 * bf2f(s1.y);
        acc.z += v1 * bf2f(s1.z); acc.w += v1 * bf2f(s1.w);
        acc.x += v2 * bf2f(s2.x); acc.y += v2 * bf2f(s2.y);
        acc.z += v2 * bf2f(s2.z); acc.w += v2 * bf2f(s2.w);
        acc.x += v3 * bf2f(s3.x); acc.y += v3 * bf2f(s3.y);
        acc.z += v3 * bf2f(s3.z); acc.w += v3 * bf2f(s3.w);
    }
    for (; j < end; j += 4) {
        const int2 p = pairs[j];
        const ushort4 s = ((const ushort4*)(src + (size_t)(p.x & 0xFFFFF) * EMB))[l];
        const float v = __int_as_float(p.y);
        acc.x += v * bf2f(s.x); acc.y += v * bf2f(s.y);
        acc.z += v * bf2f(s.z); acc.w += v * bf2f(s.w);
    }
#pragma unroll
    for (int m = 16; m <= 32; m <<= 1) {
        acc.x += __shfl_xor(acc.x, m, 64);
        acc.y += __shfl_xor(acc.y, m, 64);
        acc.z += __shfl_xor(acc.z, m, 64);
        acc.w += __shfl_xor(acc.w, m, 64);
    }
    if (g == 0) {
        ushort4 o;
        o.x = f2bf(acc.x); o.y = f2bf(acc.y);
        o.z = f2bf(acc.z); o.w = f2bf(acc.w);
        ((ushort4*)(dst + (size_t)r * EMB))[l] = o;
    }
}

// Pass 2 fused with LayerNorm + residual: y never materialized.
// After the g-combine, every lane has the full col sums for its 4 cols;
// s/s2 reduce over bits 0-3 gives row mean/var in-register.
__global__ void spmm_pull_ln(const int* __restrict__ ends,
                             const int2* __restrict__ pairs,
                             const unsigned short* __restrict__ src,
                             const float* __restrict__ ego,
                             const float* __restrict__ gamma,
                             const float* __restrict__ beta,
                             float* __restrict__ out, int nrows)
{
    const int lane = threadIdx.x & 63;
    const int wv = threadIdx.x >> 6;
    const int r = blockIdx.x * 4 + wv;
    if (r >= nrows) return;
    const int beg = (r == 0) ? 0 : ends[r - 1];
    const int end = ends[r];
    const int g = lane >> 4;
    const int l = lane & 15;
    float4 acc = make_float4(0.f, 0.f, 0.f, 0.f);
    int j = beg + g;
    for (; j + 12 < end; j += 16) {
        const int2 p0 = pairs[j];
        const int2 p1 = pairs[j + 4];
        const int2 p2 = pairs[j + 8];
        const int2 p3 = pairs[j + 12];
        const ushort4 s0 = ((const ushort4*)(src + (size_t)(p0.x & 0xFFFFF) * EMB))[l];
        const ushort4 s1 = ((const ushort4*)(src + (size_t)(p1.x & 0xFFFFF) * EMB))[l];
        const ushort4 s2 = ((const ushort4*)(src + (size_t)(p2.x & 0xFFFFF) * EMB))[l];
        const ushort4 s3 = ((const ushort4*)(src + (size_t)(p3.x & 0xFFFFF) * EMB))[l];
        const float v0 = __int_as_float(p0.y), v1 = __int_as_float(p1.y);
        const float v2 = __int_as_float(p2.y), v3 = __int_as_float(p3.y);
        acc.x += v0 * bf2f(s0.x); acc.y += v0 * bf2f(s0.y);
        acc.z += v0 * bf2f(s0.z); acc.w += v0 * bf2f(s0.w);
        acc.x += v1 * bf2f(s1.x); acc.y += v1 * bf2f(s1.y);
        acc.z += v1 * bf2f(s1.z); acc.w += v1 * bf2f(s1.w);
        acc.x += v2 * bf2f(s2.x); acc.y += v2 * bf2f(s2.y);
        acc.z += v2 * bf2f(s2.z); acc.w += v2 * bf2f(s2.w);
        acc.x += v3 * bf2f(s3.x); acc.y += v3 * bf2f(s3.y);
        acc.z += v3 * bf2f(s3.z); acc.w += v3 * bf2f(s3.w);
    }
    for (; j < end; j += 4) {
        const int2 p = pairs[j];
        const ushort4 s = ((const ushort4*)(src + (size_t)(p.x & 0xFFFFF) * EMB))[l];
        const float v = __int_as_float(p.y);
        acc.x += v * bf2f(s.x); acc.y += v * bf2f(s.y);
        acc.z += v * bf2f(s.z); acc.w += v * bf2f(s.w);
    }
#pragma unroll
    for (int m = 16; m <= 32; m <<= 1) {
        acc.x += __shfl_xor(acc.x, m, 64);
        acc.y += __shfl_xor(acc.y, m, 64);
        acc.z += __shfl_xor(acc.z, m, 64);
        acc.w += __shfl_xor(acc.w, m, 64);
    }
    // row statistics across the 16 col-groups (bits 0-3 of lane)
    float s  = acc.x + acc.y + acc.z + acc.w;
    float s2 = acc.x * acc.x + acc.y * acc.y + acc.z * acc.z + acc.w * acc.w;
#pragma unroll
    for (int m = 1; m <= 8; m <<= 1) {
        s  += __shfl_xor(s,  m, 64);
        s2 += __shfl_xor(s2, m, 64);
    }
    const float mu  = s * (1.0f / EMB);
    const float var = s2 * (1.0f / EMB) - mu * mu;
    const float inv = rsqrtf(var + LN_EPS);
    if (g == 0) {
        const float4 gm = ((const float4*)gamma)[l];
        const float4 bt = ((const float4*)beta)[l];
        const float4 eg = ((const float4*)(ego + (size_t)r * EMB))[l];
        float4 o;
        o.x = (acc.x - mu) * inv * gm.x + bt.x + eg.x;
        o.y = (acc.y - mu) * inv * gm.y + bt.y + eg.y;
        o.z = (acc.z - mu) * inv * gm.z + bt.z + eg.z;
        o.w = (acc.w - mu) * inv * gm.w + bt.w + eg.w;
        ((float4*)(out + (size_t)r * EMB))[l] = o;
    }
}

// ---------------------------------------------------------------------------
// Fallback (round-1) atomic scatter path, fp32, used only if ws too small.
__global__ void transform_kernel(const float* __restrict__ x,
                                 const float* __restrict__ W,
                                 const float* __restrict__ filt,
                                 const float* __restrict__ par,
                                 float* __restrict__ out, int nrows)
{
    __shared__ float Ws[EMB * EMB];
    const int tid = threadIdx.x;
    for (int i = tid; i < EMB * EMB; i += blockDim.x) Ws[i] = W[i];
    __syncthreads();
    const float c = par[0] * par[1];
    const int lane = tid & 63;
    const int wave = tid >> 6;
    const int r0 = blockIdx.x * 32;
    for (int rr = wave; rr < 32; rr += 4) {
        const int r = r0 + rr;
        if (r >= nrows) break;
        const float xv = x[(size_t)r * EMB + lane];
        float acc = 0.f;
#pragma unroll
        for (int k = 0; k < EMB; ++k) {
            const float xk = __shfl(xv, k, 64);
            acc += xk * Ws[k * EMB + lane];
        }
        out[(size_t)r * EMB + lane] = c * filt[r] * acc + xv;
    }
}

__global__ void spmm_scatter(const int* __restrict__ src_idx,
                             const int* __restrict__ dst_idx,
                             const float* __restrict__ vals,
                             const float* __restrict__ src,
                             float* __restrict__ dst, int nnz)
{
    const long long t = (long long)blockIdx.x * blockDim.x + threadIdx.x;
    const int e = (int)(t >> 4);
    const int l = (int)(t & 15);
    if (e >= nnz) return;
    const int s = src_idx[e];
    const int d = dst_idx[e];
    const float v = vals[e];
    const float4 xv = ((const float4*)(src + (size_t)s * EMB))[l];
    float* dp = dst + (size_t)d * EMB + l * 4;
    atomicAdd(dp + 0, v * xv.x);
    atomicAdd(dp + 1, v * xv.y);
    atomicAdd(dp + 2, v * xv.z);
    atomicAdd(dp + 3, v * xv.w);
}

__global__ void ln_residual(const float* y,
                            const float* __restrict__ ego,
                            const float* __restrict__ gamma,
                            const float* __restrict__ beta,
                            float* out, int nrows)
{
    const int lane = threadIdx.x & 63;
    const int wave = threadIdx.x >> 6;
    const int r = blockIdx.x * 4 + wave;
    if (r >= nrows) return;
    const float v = y[(size_t)r * EMB + lane];
    float s = v, s2 = v * v;
#pragma unroll
    for (int off = 32; off > 0; off >>= 1) {
        s  += __shfl_down(s,  off, 64);
        s2 += __shfl_down(s2, off, 64);
    }
    s  = __shfl(s,  0, 64);
    s2 = __shfl(s2, 0, 64);
    const float mu  = s * (1.0f / EMB);
    const float var = s2 * (1.0f / EMB) - mu * mu;
    const float inv = rsqrtf(var + LN_EPS);
    out[(size_t)r * EMB + lane] =
        (v - mu) * inv * gamma[lane] + beta[lane] + ego[(size_t)r * EMB + lane];
}

extern "C" void kernel_launch(void* const* d_in, const int* in_sizes, int n_in,
                              void* d_out, int out_size, void* d_ws, size_t ws_size,
                              hipStream_t stream)
{
    const float* ego     = (const float*)d_in[0];
    const int*   rows    = (const int*)  d_in[1];
    const int*   cols    = (const int*)  d_in[2];
    const float* vals    = (const float*)d_in[3];
    const float* w_uu    = (const float*)d_in[4];
    const float* filt_uu = (const float*)d_in[5];
    const float* par_uu  = (const float*)d_in[6];
    const float* w_ii    = (const float*)d_in[7];
    const float* filt_ii = (const float*)d_in[8];
    const float* par_ii  = (const float*)d_in[9];
    const float* gamma   = (const float*)d_in[10];
    const float* beta    = (const float*)d_in[11];
    float* out = (float*)d_out;
    const int nnz = in_sizes[1];

    const size_t emb_elems = (size_t)N_TOTAL * EMB;
    const size_t emb_bytes = emb_elems * sizeof(float);

    // Same bound as rounds 2-6 (proven available); actual use = 77.2 MB.
    const size_t need = 2 * emb_bytes + (size_t)nnz * sizeof(int2)
                        + 2 * (size_t)N_TOTAL * sizeof(int);

    const int rb = (N_TOTAL + 3) / 4;

    if (ws_size >= need) {
        // ---- fast path: two-level exact sort + bf16 pull, LN fused ------
        unsigned short* ego2b = (unsigned short*)d_ws;    // 12.8 MB
        unsigned short* hb    = ego2b + emb_elems;        // 12.8 MB
        int2*  pairs1    = (int2*)(hb + emb_elems);       // 25.6 MB
        int2*  pairs2    = pairs1 + nnz;                  // 25.6 MB
        int*   fine_ends = (int*)(pairs2 + nnz);          // 400 KB
        int*   cnt_c  = fine_ends + N_TOTAL;
        int*   cnt_r  = cnt_c + NSUP;
        int*   base_c = cnt_r + NSUP;
        int*   cur_c  = base_c + (NSUP + 1);
        int*   base_r = cur_c + NSUP;
        int*   cur_r  = base_r + (NSUP + 1);

        hipMemsetAsync(cnt_c, 0, 2 * NSUP * sizeof(int), stream);

        hist_sup<<<512, 256, 0, stream>>>(rows, cols, cnt_r, cnt_c, nnz);
        scan_sup<<<2, 256, 0, stream>>>(cnt_c, base_c, cur_c,
                                        cnt_r, base_r, cur_r);

        transform_tile<<<N_TOTAL / TR_ROWS, 256, 0, stream>>>(
            ego, w_uu, filt_uu, par_uu, w_ii, filt_ii, par_ii, ego2b);

        const int l1b = (nnz + EPB - 1) / EPB;

        // Pass 1: key = col, payload = row.  h[c] = sum val*ego2[r]  (bf16)
        build_l1<<<l1b, 256, 0, stream>>>(cols, rows, vals, cur_c, pairs1, nnz);
        sort_l2<<<NSUP, 256, 0, stream>>>(base_c, pairs1, pairs2, fine_ends);
        spmm_pull_bf16<<<rb, 256, 0, stream>>>(fine_ends, pairs2, ego2b, hb,
                                               N_TOTAL);

        // Pass 2: key = row, payload = col.  out = LN(A h) + ego, fused.
        build_l1<<<l1b, 256, 0, stream>>>(rows, cols, vals, cur_r, pairs1, nnz);
        sort_l2<<<NSUP, 256, 0, stream>>>(base_r, pairs1, pairs2, fine_ends);
        spmm_pull_ln<<<rb, 256, 0, stream>>>(fine_ends, pairs2, hb,
                                             ego, gamma, beta, out, N_TOTAL);
    } else {
        // ---------------- fallback: atomic scatter (round-1, fp32) -------
        float* ego2 = (float*)d_ws;
        float* h    = ego2 + emb_elems;
        hipMemsetAsync(h,   0, emb_bytes, stream);
        hipMemsetAsync(out, 0, emb_bytes, stream);

        transform_kernel<<<(N_USERS + 31) / 32, 256, 0, stream>>>(
            ego, w_uu, filt_uu, par_uu, ego2, N_USERS);
        transform_kernel<<<(N_ITEMS + 31) / 32, 256, 0, stream>>>(
            ego + (size_t)N_USERS * EMB, w_ii, filt_ii, par_ii,
            ego2 + (size_t)N_USERS * EMB, N_ITEMS);

        const long long thr = (long long)nnz * 16;
        const int sblocks = (int)((thr + 255) / 256);
        spmm_scatter<<<sblocks, 256, 0, stream>>>(rows, cols, vals, ego2, h, nnz);
        spmm_scatter<<<sblocks, 256, 0, stream>>>(cols, rows, vals, h, out, nnz);

        ln_residual<<<rb, 256, 0, stream>>>(out, ego, gamma, beta, out, N_TOTAL);
    }
}

// Round 8
// 432.740 us; speedup vs baseline: 7.4487x; 1.0610x over previous
//
#include <hip/hip_runtime.h>

#define N_USERS 60000
#define N_ITEMS 40000
#define N_TOTAL 100000
#define EMB 64
#define LN_EPS 1e-5f

#define KPS 512                                  // keys per super-bucket
#define NSUP ((N_TOTAL + KPS - 1) / KPS)         // 196
#define EPB 4096                                 // edges per build_l1 block
#define TR_ROWS 32                               // rows per transform block
#define XPITCH 68                                // x-tile pitch (floats)

// bf16 helpers (exact shift for bf16->f32; RNE for f32->bf16)
__device__ __forceinline__ float bf2f(unsigned short h)
{ return __uint_as_float(((unsigned)h) << 16); }
__device__ __forceinline__ unsigned short f2bf(float f)
{
    unsigned u = __float_as_uint(f);
    return (unsigned short)((u + 0x7FFFu + ((u >> 16) & 1u)) >> 16);
}

// ---------------------------------------------------------------------------
// ego2[r,:] = c * filt[r] * (x[r,:] @ W) + x[r,:]   (bf16 output)
__global__ void transform_tile(const float* __restrict__ x,
                               const float* __restrict__ w_uu,
                               const float* __restrict__ filt_uu,
                               const float* __restrict__ par_uu,
                               const float* __restrict__ w_ii,
                               const float* __restrict__ filt_ii,
                               const float* __restrict__ par_ii,
                               unsigned short* __restrict__ out)
{
    __shared__ float Wls[EMB * EMB];             // 16 KB
    __shared__ float xs[TR_ROWS * XPITCH];       // 8.7 KB
    const int tid = threadIdx.x;
    const int r0 = blockIdx.x * TR_ROWS;
    const int itm = (r0 >= N_USERS);             // uniform per block
    const float* W  = itm ? w_ii : w_uu;
    const float* fb = itm ? filt_ii : filt_uu;
    const int foff  = itm ? N_USERS : 0;
    const float c   = itm ? par_ii[0] * par_ii[1] : par_uu[0] * par_uu[1];

    for (int i = tid; i < EMB * EMB / 4; i += 256)
        ((float4*)Wls)[i] = ((const float4*)W)[i];
    for (int i = tid; i < TR_ROWS * 16; i += 256) {
        const float4 v = ((const float4*)x)[r0 * 16 + i];
        *(float4*)&xs[(i >> 4) * XPITCH + (i & 15) * 4] = v;
    }
    __syncthreads();

    const int lane = tid & 63;
    const int wv = tid >> 6;
    const int rg = lane >> 4;
    const int j  = lane & 15;

#pragma unroll
    for (int it = 0; it < 2; ++it) {
        const int rl = wv * 8 + it * 4 + rg;
        const int row = r0 + rl;
        float4 acc = make_float4(0.f, 0.f, 0.f, 0.f);
#pragma unroll 8
        for (int k = 0; k < EMB; ++k) {
            const float xb = xs[rl * XPITCH + k];
            const float4 w4 = *(const float4*)&Wls[k * EMB + 4 * j];
            acc.x += xb * w4.x; acc.y += xb * w4.y;
            acc.z += xb * w4.z; acc.w += xb * w4.w;
        }
        const float cf = c * fb[row - foff];
        const float4 xv = *(const float4*)&xs[rl * XPITCH + 4 * j];
        ushort4 o;
        o.x = f2bf(cf * acc.x + xv.x);
        o.y = f2bf(cf * acc.y + xv.y);
        o.z = f2bf(cf * acc.z + xv.z);
        o.w = f2bf(cf * acc.w + xv.w);
        *(ushort4*)&out[(size_t)row * EMB + 4 * j] = o;
    }
}

// ---------------------------------------------------------------------------
// Super-bucket histograms for BOTH orderings. LDS-local then merge.
__global__ void hist_sup(const int* __restrict__ rows,
                         const int* __restrict__ cols,
                         int* __restrict__ cnt_r,
                         int* __restrict__ cnt_c, int nnz)
{
    __shared__ int hr[NSUP], hc[NSUP];
    const int tid = threadIdx.x;
    for (int i = tid; i < NSUP; i += 256) { hr[i] = 0; hc[i] = 0; }
    __syncthreads();
    for (int e = blockIdx.x * 256 + tid; e < nnz; e += gridDim.x * 256) {
        atomicAdd(&hr[rows[e] >> 9], 1);
        atomicAdd(&hc[cols[e] >> 9], 1);
    }
    __syncthreads();
    for (int i = tid; i < NSUP; i += 256) {
        if (hr[i]) atomicAdd(&cnt_r[i], hr[i]);
        if (hc[i]) atomicAdd(&cnt_c[i], hc[i]);
    }
}

// Exclusive scan of the NSUP counters. grid=2: block 0 = cols, 1 = rows.
__global__ void scan_sup(const int* __restrict__ cnt_c, int* __restrict__ base_c,
                         int* __restrict__ cur_c,
                         const int* __restrict__ cnt_r, int* __restrict__ base_r,
                         int* __restrict__ cur_r)
{
    const int* cnt = blockIdx.x ? cnt_r : cnt_c;
    int* base = blockIdx.x ? base_r : base_c;
    int* cur  = blockIdx.x ? cur_r  : cur_c;
    __shared__ int wsum[4];
    const int lane = threadIdx.x & 63;
    const int wv = threadIdx.x >> 6;
    const int i = threadIdx.x;
    const int v = (i < NSUP) ? cnt[i] : 0;
    int incl = v;
#pragma unroll
    for (int off = 1; off < 64; off <<= 1) {
        const int t = __shfl_up(incl, off, 64);
        if (lane >= off) incl += t;
    }
    if (lane == 63) wsum[wv] = incl;
    __syncthreads();
    int woff = 0;
    for (int w = 0; w < wv; ++w) woff += wsum[w];
    const int excl = woff + incl - v;
    if (i < NSUP) { base[i] = excl; cur[i] = excl; }
    if (i == 0) base[NSUP] = wsum[0] + wsum[1] + wsum[2] + wsum[3];
}

// ---------------------------------------------------------------------------
// Level 1: group a 4096-edge chunk by super-bucket in LDS, reserve global
// space per (block, sup) with one atomic, stream grouped bursts out.
// Payload: other(17b) | keylow9 << 20.
__global__ void __launch_bounds__(256, 1)
build_l1(const int* __restrict__ key,
         const int* __restrict__ other,
         const float* __restrict__ vals,
         int* __restrict__ cursor,
         int2* __restrict__ pairs1, int nnz)
{
    __shared__ int2 stage[EPB];                  // 32 KB
    __shared__ unsigned char sg[EPB];            // 4 KB
    __shared__ int hist[NSUP];
    __shared__ int sexcl[NSUP];
    __shared__ int gbase[NSUP];
    __shared__ int lcur[NSUP];
    __shared__ int wsum[4];

    const int tid = threadIdx.x;
    const int e0 = blockIdx.x * EPB;
    const int ecnt = min(EPB, nnz - e0);

    for (int i = tid; i < NSUP; i += 256) hist[i] = 0;
    __syncthreads();

    int myk[16], myo[16];
    float myv[16];
#pragma unroll
    for (int i = 0; i < 16; ++i) {
        const int s = tid + i * 256;
        if (s < ecnt) {
            const int e = e0 + s;
            myk[i] = key[e]; myo[i] = other[e]; myv[i] = vals[e];
            atomicAdd(&hist[myk[i] >> 9], 1);
        } else myk[i] = -1;
    }
    __syncthreads();

    {
        const int lane = tid & 63;
        const int wv = tid >> 6;
        const int v = (tid < NSUP) ? hist[tid] : 0;
        int incl = v;
#pragma unroll
        for (int off = 1; off < 64; off <<= 1) {
            const int t = __shfl_up(incl, off, 64);
            if (lane >= off) incl += t;
        }
        if (lane == 63) wsum[wv] = incl;
        __syncthreads();
        int woff = 0;
        for (int w = 0; w < wv; ++w) woff += wsum[w];
        const int excl = woff + incl - v;
        if (tid < NSUP) {
            sexcl[tid] = excl;
            lcur[tid] = excl;
            gbase[tid] = v ? atomicAdd(&cursor[tid], v) : 0;
        }
    }
    __syncthreads();

#pragma unroll
    for (int i = 0; i < 16; ++i) {
        if (myk[i] >= 0) {
            const int g = myk[i] >> 9;
            const int s = atomicAdd(&lcur[g], 1);
            stage[s] = make_int2(myo[i] | ((myk[i] & (KPS - 1)) << 20),
                                 __float_as_int(myv[i]));
            sg[s] = (unsigned char)g;
        }
    }
    __syncthreads();

    for (int s = tid; s < ecnt; s += 256) {
        const int g = sg[s];
        pairs1[gbase[g] + (s - sexcl[g])] = stage[s];
    }
}

// Level 2: one 1024-thread block per super-bucket (16 waves: 4x the latency
// hiding of the 256-thread version; grid is only NSUP=196 so per-block
// parallelism is what fills the machine). Exact counting sort of the
// region; emits per-key END offsets.
__global__ void sort_l2(const int* __restrict__ base,
                        const int2* __restrict__ pairs1,
                        int2* __restrict__ pairs2,
                        int* __restrict__ fine_ends)
{
    __shared__ int cnt[KPS];
    __shared__ int cur[KPS];
    __shared__ int csum[8];
    const int sup = blockIdx.x;
    const int beg = base[sup];
    const int end = base[sup + 1];
    const int tid = threadIdx.x;
    const int lane = tid & 63;
    const int wv = tid >> 6;                     // 0..15

    if (tid < KPS) cnt[tid] = 0;
    __syncthreads();
    for (int j = beg + tid; j < end; j += 1024)
        atomicAdd(&cnt[pairs1[j].x >> 20], 1);
    __syncthreads();

    // scan 512 counters: 8 chunks of 64, waves 0..7 (one chunk each)
    int orig = 0;
    if (wv < 8) {
        const int i = wv * 64 + lane;
        const int v = cnt[i];
        orig = v;
        int incl = v;
#pragma unroll
        for (int off = 1; off < 64; off <<= 1) {
            const int u = __shfl_up(incl, off, 64);
            if (lane >= off) incl += u;
        }
        cnt[i] = incl;                           // chunk-local inclusive
        if (lane == 63) csum[wv] = incl;
    }
    __syncthreads();
    if (tid == 0) {
        int run = 0;
#pragma unroll
        for (int c = 0; c < 8; ++c) { const int t = csum[c]; csum[c] = run; run += t; }
    }
    __syncthreads();
    if (wv < 8) {
        const int i = wv * 64 + lane;
        const int incl_g = csum[wv] + cnt[i];
        cur[i] = incl_g - orig;                  // exclusive
        const int k = sup * KPS + i;
        if (k < N_TOTAL) fine_ends[k] = beg + incl_g;
    }
    __syncthreads();

    for (int j = beg + tid; j < end; j += 1024) {
        const int2 p = pairs1[j];
        const int pos = beg + atomicAdd(&cur[p.x >> 20], 1);
        pairs2[pos] = p;
    }
}

// ---------------------------------------------------------------------------
// U consecutive (stride-4) edges for one 16-lane group: gather + FMA.
template <int U>
__device__ __forceinline__ void pull_step(const int2* __restrict__ pairs, int j,
                                          const unsigned short* __restrict__ src,
                                          int l, float4& acc)
{
    int2 p[U];
#pragma unroll
    for (int u = 0; u < U; ++u) p[u] = pairs[j + 4 * u];
    ushort4 s[U];
#pragma unroll
    for (int u = 0; u < U; ++u)
        s[u] = ((const ushort4*)(src + (size_t)(p[u].x & 0xFFFFF) * EMB))[l];
#pragma unroll
    for (int u = 0; u < U; ++u) {
        const float v = __int_as_float(p[u].y);
        acc.x += v * bf2f(s[u].x); acc.y += v * bf2f(s[u].y);
        acc.z += v * bf2f(s[u].z); acc.w += v * bf2f(s[u].w);
    }
}

// Pass 1: dst bf16. 4 edge-groups x 16 lanes x bf16x4; unroll tiers 8/4/1.
__global__ void spmm_pull_bf16(const int* __restrict__ ends,
                               const int2* __restrict__ pairs,
                               const unsigned short* __restrict__ src,
                               unsigned short* __restrict__ dst, int nrows)
{
    const int lane = threadIdx.x & 63;
    const int wv = threadIdx.x >> 6;
    const int r = blockIdx.x * 4 + wv;
    if (r >= nrows) return;
    const int beg = (r == 0) ? 0 : ends[r - 1];
    const int end = ends[r];
    const int g = lane >> 4;
    const int l = lane & 15;
    float4 acc = make_float4(0.f, 0.f, 0.f, 0.f);
    int j = beg + g;
    for (; j + 28 < end; j += 32) pull_step<8>(pairs, j, src, l, acc);
    for (; j + 12 < end; j += 16) pull_step<4>(pairs, j, src, l, acc);
    for (; j < end; j += 4)       pull_step<1>(pairs, j, src, l, acc);
#pragma unroll
    for (int m = 16; m <= 32; m <<= 1) {
        acc.x += __shfl_xor(acc.x, m, 64);
        acc.y += __shfl_xor(acc.y, m, 64);
        acc.z += __shfl_xor(acc.z, m, 64);
        acc.w += __shfl_xor(acc.w, m, 64);
    }
    if (g == 0) {
        ushort4 o;
        o.x = f2bf(acc.x); o.y = f2bf(acc.y);
        o.z = f2bf(acc.z); o.w = f2bf(acc.w);
        ((ushort4*)(dst + (size_t)r * EMB))[l] = o;
    }
}

// Pass 2 fused with LayerNorm + residual.
__global__ void spmm_pull_ln(const int* __restrict__ ends,
                             const int2* __restrict__ pairs,
                             const unsigned short* __restrict__ src,
                             const float* __restrict__ ego,
                             const float* __restrict__ gamma,
                             const float* __restrict__ beta,
                             float* __restrict__ out, int nrows)
{
    const int lane = threadIdx.x & 63;
    const int wv = threadIdx.x >> 6;
    const int r = blockIdx.x * 4 + wv;
    if (r >= nrows) return;
    const int beg = (r == 0) ? 0 : ends[r - 1];
    const int end = ends[r];
    const int g = lane >> 4;
    const int l = lane & 15;
    float4 acc = make_float4(0.f, 0.f, 0.f, 0.f);
    int j = beg + g;
    for (; j + 28 < end; j += 32) pull_step<8>(pairs, j, src, l, acc);
    for (; j + 12 < end; j += 16) pull_step<4>(pairs, j, src, l, acc);
    for (; j < end; j += 4)       pull_step<1>(pairs, j, src, l, acc);
#pragma unroll
    for (int m = 16; m <= 32; m <<= 1) {
        acc.x += __shfl_xor(acc.x, m, 64);
        acc.y += __shfl_xor(acc.y, m, 64);
        acc.z += __shfl_xor(acc.z, m, 64);
        acc.w += __shfl_xor(acc.w, m, 64);
    }
    // row statistics across the 16 col-groups (bits 0-3 of lane)
    float s  = acc.x + acc.y + acc.z + acc.w;
    float s2 = acc.x * acc.x + acc.y * acc.y + acc.z * acc.z + acc.w * acc.w;
#pragma unroll
    for (int m = 1; m <= 8; m <<= 1) {
        s  += __shfl_xor(s,  m, 64);
        s2 += __shfl_xor(s2, m, 64);
    }
    const float mu  = s * (1.0f / EMB);
    const float var = s2 * (1.0f / EMB) - mu * mu;
    const float inv = rsqrtf(var + LN_EPS);
    if (g == 0) {
        const float4 gm = ((const float4*)gamma)[l];
        const float4 bt = ((const float4*)beta)[l];
        const float4 eg = ((const float4*)(ego + (size_t)r * EMB))[l];
        float4 o;
        o.x = (acc.x - mu) * inv * gm.x + bt.x + eg.x;
        o.y = (acc.y - mu) * inv * gm.y + bt.y + eg.y;
        o.z = (acc.z - mu) * inv * gm.z + bt.z + eg.z;
        o.w = (acc.w - mu) * inv * gm.w + bt.w + eg.w;
        ((float4*)(out + (size_t)r * EMB))[l] = o;
    }
}

// ---------------------------------------------------------------------------
// Fallback (round-1) atomic scatter path, fp32, used only if ws too small.
__global__ void transform_kernel(const float* __restrict__ x,
                                 const float* __restrict__ W,
                                 const float* __restrict__ filt,
                                 const float* __restrict__ par,
                                 float* __restrict__ out, int nrows)
{
    __shared__ float Ws[EMB * EMB];
    const int tid = threadIdx.x;
    for (int i = tid; i < EMB * EMB; i += blockDim.x) Ws[i] = W[i];
    __syncthreads();
    const float c = par[0] * par[1];
    const int lane = tid & 63;
    const int wave = tid >> 6;
    const int r0 = blockIdx.x * 32;
    for (int rr = wave; rr < 32; rr += 4) {
        const int r = r0 + rr;
        if (r >= nrows) break;
        const float xv = x[(size_t)r * EMB + lane];
        float acc = 0.f;
#pragma unroll
        for (int k = 0; k < EMB; ++k) {
            const float xk = __shfl(xv, k, 64);
            acc += xk * Ws[k * EMB + lane];
        }
        out[(size_t)r * EMB + lane] = c * filt[r] * acc + xv;
    }
}

__global__ void spmm_scatter(const int* __restrict__ src_idx,
                             const int* __restrict__ dst_idx,
                             const float* __restrict__ vals,
                             const float* __restrict__ src,
                             float* __restrict__ dst, int nnz)
{
    const long long t = (long long)blockIdx.x * blockDim.x + threadIdx.x;
    const int e = (int)(t >> 4);
    const int l = (int)(t & 15);
    if (e >= nnz) return;
    const int s = src_idx[e];
    const int d = dst_idx[e];
    const float v = vals[e];
    const float4 xv = ((const float4*)(src + (size_t)s * EMB))[l];
    float* dp = dst + (size_t)d * EMB + l * 4;
    atomicAdd(dp + 0, v * xv.x);
    atomicAdd(dp + 1, v * xv.y);
    atomicAdd(dp + 2, v * xv.z);
    atomicAdd(dp + 3, v * xv.w);
}

__global__ void ln_residual(const float* y,
                            const float* __restrict__ ego,
                            const float* __restrict__ gamma,
                            const float* __restrict__ beta,
                            float* out, int nrows)
{
    const int lane = threadIdx.x & 63;
    const int wave = threadIdx.x >> 6;
    const int r = blockIdx.x * 4 + wave;
    if (r >= nrows) return;
    const float v = y[(size_t)r * EMB + lane];
    float s = v, s2 = v * v;
#pragma unroll
    for (int off = 32; off > 0; off >>= 1) {
        s  += __shfl_down(s,  off, 64);
        s2 += __shfl_down(s2, off, 64);
    }
    s  = __shfl(s,  0, 64);
    s2 = __shfl(s2, 0, 64);
    const float mu  = s * (1.0f / EMB);
    const float var = s2 * (1.0f / EMB) - mu * mu;
    const float inv = rsqrtf(var + LN_EPS);
    out[(size_t)r * EMB + lane] =
        (v - mu) * inv * gamma[lane] + beta[lane] + ego[(size_t)r * EMB + lane];
}

extern "C" void kernel_launch(void* const* d_in, const int* in_sizes, int n_in,
                              void* d_out, int out_size, void* d_ws, size_t ws_size,
                              hipStream_t stream)
{
    const float* ego     = (const float*)d_in[0];
    const int*   rows    = (const int*)  d_in[1];
    const int*   cols    = (const int*)  d_in[2];
    const float* vals    = (const float*)d_in[3];
    const float* w_uu    = (const float*)d_in[4];
    const float* filt_uu = (const float*)d_in[5];
    const float* par_uu  = (const float*)d_in[6];
    const float* w_ii    = (const float*)d_in[7];
    const float* filt_ii = (const float*)d_in[8];
    const float* par_ii  = (const float*)d_in[9];
    const float* gamma   = (const float*)d_in[10];
    const float* beta    = (const float*)d_in[11];
    float* out = (float*)d_out;
    const int nnz = in_sizes[1];

    const size_t emb_elems = (size_t)N_TOTAL * EMB;
    const size_t emb_bytes = emb_elems * sizeof(float);

    // Same bound as rounds 2-7 (proven available); actual use = 77.2 MB.
    const size_t need = 2 * emb_bytes + (size_t)nnz * sizeof(int2)
                        + 2 * (size_t)N_TOTAL * sizeof(int);

    const int rb = (N_TOTAL + 3) / 4;

    if (ws_size >= need) {
        // ---- fast path: two-level exact sort + bf16 pull, LN fused ------
        unsigned short* ego2b = (unsigned short*)d_ws;    // 12.8 MB
        unsigned short* hb    = ego2b + emb_elems;        // 12.8 MB
        int2*  pairs1    = (int2*)(hb + emb_elems);       // 25.6 MB
        int2*  pairs2    = pairs1 + nnz;                  // 25.6 MB
        int*   fine_ends = (int*)(pairs2 + nnz);          // 400 KB
        int*   cnt_c  = fine_ends + N_TOTAL;
        int*   cnt_r  = cnt_c + NSUP;
        int*   base_c = cnt_r + NSUP;
        int*   cur_c  = base_c + (NSUP + 1);
        int*   base_r = cur_c + NSUP;
        int*   cur_r  = base_r + (NSUP + 1);

        hipMemsetAsync(cnt_c, 0, 2 * NSUP * sizeof(int), stream);

        hist_sup<<<512, 256, 0, stream>>>(rows, cols, cnt_r, cnt_c, nnz);
        scan_sup<<<2, 256, 0, stream>>>(cnt_c, base_c, cur_c,
                                        cnt_r, base_r, cur_r);

        transform_tile<<<N_TOTAL / TR_ROWS, 256, 0, stream>>>(
            ego, w_uu, filt_uu, par_uu, w_ii, filt_ii, par_ii, ego2b);

        const int l1b = (nnz + EPB - 1) / EPB;

        // Pass 1: key = col, payload = row.  h[c] = sum val*ego2[r]  (bf16)
        build_l1<<<l1b, 256, 0, stream>>>(cols, rows, vals, cur_c, pairs1, nnz);
        sort_l2<<<NSUP, 1024, 0, stream>>>(base_c, pairs1, pairs2, fine_ends);
        spmm_pull_bf16<<<rb, 256, 0, stream>>>(fine_ends, pairs2, ego2b, hb,
                                               N_TOTAL);

        // Pass 2: key = row, payload = col.  out = LN(A h) + ego, fused.
        build_l1<<<l1b, 256, 0, stream>>>(rows, cols, vals, cur_r, pairs1, nnz);
        sort_l2<<<NSUP, 1024, 0, stream>>>(base_r, pairs1, pairs2, fine_ends);
        spmm_pull_ln<<<rb, 256, 0, stream>>>(fine_ends, pairs2, hb,
                                             ego, gamma, beta, out, N_TOTAL);
    } else {
        // ---------------- fallback: atomic scatter (round-1, fp32) -------
        float* ego2 = (float*)d_ws;
        float* h    = ego2 + emb_elems;
        hipMemsetAsync(h,   0, emb_bytes, stream);
        hipMemsetAsync(out, 0, emb_bytes, stream);

        transform_kernel<<<(N_USERS + 31) / 32, 256, 0, stream>>>(
            ego, w_uu, filt_uu, par_uu, ego2, N_USERS);
        transform_kernel<<<(N_ITEMS + 31) / 32, 256, 0, stream>>>(
            ego + (size_t)N_USERS * EMB, w_ii, filt_ii, par_ii,
            ego2 + (size_t)N_USERS * EMB, N_ITEMS);

        const long long thr = (long long)nnz * 16;
        const int sblocks = (int)((thr + 255) / 256);
        spmm_scatter<<<sblocks, 256, 0, stream>>>(rows, cols, vals, ego2, h, nnz);
        spmm_scatter<<<sblocks, 256, 0, stream>>>(cols, rows, vals, h, out, nnz);

        ln_residual<<<rb, 256, 0, stream>>>(out, ego, gamma, beta, out, N_TOTAL);
    }
}